// Round 3
// baseline (1273.665 us; speedup 1.0000x reference)
//
#include <hip/hip_runtime.h>
#include <math.h>

#define Bsz 64
#define Himg 224
#define HS (Himg*Himg)        // 50176
#define PW 111
#define PP (PW*PW)            // 12321
#define Fn 8
#define FEAT (Fn*PP)          // 98568
#define N1 512
#define N2 256
#define N3 1000
#define KC 16
#define CHUNK 384
#define NCH 257               // ceil(FEAT/CHUNK)

// async global->LDS, 16B per lane; lds base must be wave-uniform
#define GLOAD_LDS16(g, l)                                                     \
  __builtin_amdgcn_global_load_lds(                                           \
      (const __attribute__((address_space(1))) void*)(g),                     \
      (__attribute__((address_space(3))) void*)(l), 16, 0, 0)

// ---------------- channel sum: s[b,y,x] = sum_c x[b,c,y,x] (float4) --------
__global__ void k_chsum(const float4* __restrict__ x, float4* __restrict__ s) {
  int i = blockIdx.x * 256 + threadIdx.x;
  const int HQ = HS / 4;
  if (i >= Bsz * HQ) return;
  int b = i / HQ, p = i - b * HQ;
  const float4* xb = x + (size_t)b * 3 * HQ + p;
  float4 a = xb[0], c = xb[HQ], d = xb[2 * HQ];
  s[i] = make_float4(a.x + c.x + d.x, a.y + c.y + d.y,
                     a.z + c.z + d.z, a.w + c.w + d.w);
}

// ------------- conv3x3 (8 filt) + relu + maxpool2x2 -> flat ----------------
__global__ void k_convpool(const float* __restrict__ s, const float* __restrict__ filt,
                           float* __restrict__ flat) {
  int i = blockIdx.x * 256 + threadIdx.x;
  if (i >= Bsz * PP) return;
  int b = i / PP, r = i - b * PP;
  int py = r / PW, px = r - py * PW;
  const float* sp = s + (size_t)b * HS + (size_t)(2 * py) * Himg + 2 * px;
  float p[4][4];
#pragma unroll
  for (int dy = 0; dy < 4; dy++)
#pragma unroll
    for (int dx = 0; dx < 4; dx++)
      p[dy][dx] = sp[dy * Himg + dx];
  float* outb = flat + (size_t)b * FEAT + r;
#pragma unroll
  for (int f = 0; f < Fn; f++) {
    float mx = 0.f;  // relu floor: max(0, conv...) == max over relu'd convs
#pragma unroll
    for (int oy = 0; oy < 2; oy++)
#pragma unroll
      for (int ox = 0; ox < 2; ox++) {
        float c = 0.f;
#pragma unroll
        for (int dy = 0; dy < 3; dy++)
#pragma unroll
          for (int dx = 0; dx < 3; dx++)
            c = fmaf(p[oy + dy][ox + dx], filt[f * 9 + dy * 3 + dx], c);
        mx = fmaxf(mx, c);
      }
    outb[(size_t)f * PP] = mx;
  }
}

// ---------------- GEMM1 split-K partials: (64 x K) @ (K x 512) -------------
// grid (4 n-tiles of 128 cols, NCH k-chunks), block 256 threads (4 waves).
// W staged direct-to-LDS via global_load_lds (async, no VGPR round-trip);
// A (4KB/step) register-staged: load issued before compute, LDS write after.
__global__ void __launch_bounds__(256, 4) k_gemm1(const float* __restrict__ A,
                                                  const float* __restrict__ W,
                                                  float* __restrict__ partial) {
  __shared__ float Wt[2][KC][128];   // [k][n]  16 KB
  __shared__ float At[2][KC][64];    // [k][m]   8 KB
  const int t = threadIdx.x;
  const int wv = t >> 6;
  const int lane = t & 63;
  const int col0 = blockIdx.x * 128;
  const int c = blockIdx.y;
  const int k0 = c * CHUNK;
  const int kend = min(k0 + CHUNK, FEAT);
  const int klen = kend - k0;
  const int nfull = klen >> 4;
  const int rem = klen & 15;         // 0 or 8 (FEAT % 8 == 0)
  // compute mapping: thread = 8m x 4n
  const int cg = t & 31;
  const int mg = t >> 5;
  // A staging: thread reads A[am][k0+ak..+3] (float4, 64B-coalesced groups)
  const int am = t >> 2;
  const int ak = (t & 3) * 4;
  // W lds-direct: wave wv covers rows 4wv..4wv+3 of the 16x128 tile
  const int wrow = lane >> 5;        // 0..1 within a call
  const int wcol = (lane & 31) * 4;

  auto stageW = [&](int buf, int kt) {
    const float* g0 = W + (size_t)(kt + wv * 4 + wrow) * N1 + col0 + wcol;
    GLOAD_LDS16(g0, &Wt[buf][wv * 4][0]);
    GLOAD_LDS16(g0 + 2 * N1, &Wt[buf][wv * 4 + 2][0]);
  };
  float4 pa;
  auto loadA = [&](int kt) {
    pa = *(const float4*)(A + (size_t)am * FEAT + kt + ak);
  };
  auto writeA = [&](int buf) {
    At[buf][ak + 0][am] = pa.x;
    At[buf][ak + 1][am] = pa.y;
    At[buf][ak + 2][am] = pa.z;
    At[buf][ak + 3][am] = pa.w;
  };

  float4 acc[8];
#pragma unroll
  for (int i = 0; i < 8; i++) acc[i] = make_float4(0.f, 0.f, 0.f, 0.f);

  // prologue: stage step 0
  if (nfull > 0) {
    stageW(0, k0);
    loadA(k0);
    writeA(0);
  }
  __syncthreads();

  for (int s = 0; s < nfull; s++) {
    const int buf = s & 1;
    const bool more = (s + 1) < nfull;
    if (more) {
      stageW(buf ^ 1, k0 + (s + 1) * KC);  // async -> LDS, drains at barrier
      loadA(k0 + (s + 1) * KC);            // -> regs, written after compute
    }
#pragma unroll
    for (int k = 0; k < KC; k++) {
      float4 a0 = *(const float4*)&At[buf][k][mg * 8];
      float4 a1 = *(const float4*)&At[buf][k][mg * 8 + 4];
      float4 w = *(const float4*)&Wt[buf][k][cg * 4];
#pragma unroll
      for (int i = 0; i < 4; i++) {
        float a = (i == 0) ? a0.x : (i == 1) ? a0.y : (i == 2) ? a0.z : a0.w;
        acc[i].x = fmaf(a, w.x, acc[i].x);
        acc[i].y = fmaf(a, w.y, acc[i].y);
        acc[i].z = fmaf(a, w.z, acc[i].z);
        acc[i].w = fmaf(a, w.w, acc[i].w);
      }
#pragma unroll
      for (int i = 0; i < 4; i++) {
        float a = (i == 0) ? a1.x : (i == 1) ? a1.y : (i == 2) ? a1.z : a1.w;
        acc[4 + i].x = fmaf(a, w.x, acc[4 + i].x);
        acc[4 + i].y = fmaf(a, w.y, acc[4 + i].y);
        acc[4 + i].z = fmaf(a, w.z, acc[4 + i].z);
        acc[4 + i].w = fmaf(a, w.w, acc[4 + i].w);
      }
    }
    if (more) writeA(buf ^ 1);
    __syncthreads();
  }

  if (rem) {  // last chunk only: zero-padded guarded 16-k step (reg path)
    const int kt = k0 + nfull * KC;
    const int buf = nfull & 1;
    // A (zero pad beyond kend)
    pa = make_float4(0.f, 0.f, 0.f, 0.f);
    if (kt + ak < kend) loadA(kt);
    writeA(buf);
    // W: thread covers row kr, 8 cols
    const int kr = t >> 4;
    const int cq = (t & 15) * 8;
    float4 w0 = make_float4(0.f, 0.f, 0.f, 0.f), w1 = w0;
    if (kt + kr < kend) {
      const float* wp = W + (size_t)(kt + kr) * N1 + col0 + cq;
      w0 = *(const float4*)wp;
      w1 = *(const float4*)(wp + 4);
    }
    *(float4*)&Wt[buf][kr][cq] = w0;
    *(float4*)&Wt[buf][kr][cq + 4] = w1;
    __syncthreads();
#pragma unroll
    for (int k = 0; k < KC; k++) {
      float4 a0 = *(const float4*)&At[buf][k][mg * 8];
      float4 a1 = *(const float4*)&At[buf][k][mg * 8 + 4];
      float4 w = *(const float4*)&Wt[buf][k][cg * 4];
#pragma unroll
      for (int i = 0; i < 4; i++) {
        float a = (i == 0) ? a0.x : (i == 1) ? a0.y : (i == 2) ? a0.z : a0.w;
        acc[i].x = fmaf(a, w.x, acc[i].x);
        acc[i].y = fmaf(a, w.y, acc[i].y);
        acc[i].z = fmaf(a, w.z, acc[i].z);
        acc[i].w = fmaf(a, w.w, acc[i].w);
      }
#pragma unroll
      for (int i = 0; i < 4; i++) {
        float a = (i == 0) ? a1.x : (i == 1) ? a1.y : (i == 2) ? a1.z : a1.w;
        acc[4 + i].x = fmaf(a, w.x, acc[4 + i].x);
        acc[4 + i].y = fmaf(a, w.y, acc[4 + i].y);
        acc[4 + i].z = fmaf(a, w.z, acc[4 + i].z);
        acc[4 + i].w = fmaf(a, w.w, acc[4 + i].w);
      }
    }
  }

  float* pp = partial + ((size_t)c * Bsz + mg * 8) * N1 + col0 + cg * 4;
#pragma unroll
  for (int i = 0; i < 8; i++)
    *(float4*)(pp + (size_t)i * N1) = acc[i];
}

// -------------- reduce partials + bias + relu -> h1 [64,512] ---------------
__global__ void k_red1(const float* __restrict__ partial, const float* __restrict__ b1,
                       float* __restrict__ h1) {
  int i = blockIdx.x * 256 + threadIdx.x;
  if (i >= Bsz * N1) return;
  float sum = 0.f;
  for (int c = 0; c < NCH; c++) sum += partial[(size_t)c * Bsz * N1 + i];
  int n = i & (N1 - 1);
  h1[i] = fmaxf(sum + b1[n], 0.f);
}

// -------------- GEMM2: h2 = relu(h1 @ W2 + b2), [64,256] -------------------
__global__ void __launch_bounds__(256) k_gemm2(const float* __restrict__ h1,
                                               const float* __restrict__ W2,
                                               const float* __restrict__ b2,
                                               float* __restrict__ h2) {
  const int m = blockIdx.x;
  const int t = threadIdx.x;
  __shared__ float a[N1];
  a[t] = h1[(size_t)m * N1 + t];
  a[256 + t] = h1[(size_t)m * N1 + 256 + t];
  __syncthreads();
  float sum = b2[t];
#pragma unroll 8
  for (int k = 0; k < N1; k++) sum = fmaf(a[k], W2[(size_t)k * N2 + t], sum);
  h2[(size_t)m * N2 + t] = fmaxf(sum, 0.f);
}

// -------------- GEMM3 + softmax: out = softmax(h2 @ Wo + bo) ---------------
__global__ void __launch_bounds__(256) k_out(const float* __restrict__ h2,
                                             const float* __restrict__ Wo,
                                             const float* __restrict__ bo,
                                             float* __restrict__ out) {
  const int m = blockIdx.x;
  const int t = threadIdx.x;
  __shared__ float a[N2];
  __shared__ float red[8];
  a[t] = h2[(size_t)m * N2 + t];
  __syncthreads();
  float vals[4];
  float vmax = -3.4e38f;
#pragma unroll
  for (int j = 0; j < 4; j++) {
    int n = j * 256 + t;
    float sum = -3.4e38f;
    if (n < N3) {
      sum = bo[n];
#pragma unroll 8
      for (int k = 0; k < N2; k++) sum = fmaf(a[k], Wo[(size_t)k * N3 + n], sum);
    }
    vals[j] = sum;
    vmax = fmaxf(vmax, sum);
  }
#pragma unroll
  for (int off = 32; off > 0; off >>= 1) vmax = fmaxf(vmax, __shfl_xor(vmax, off));
  const int wid = t >> 6;
  if ((t & 63) == 0) red[wid] = vmax;
  __syncthreads();
  vmax = fmaxf(fmaxf(red[0], red[1]), fmaxf(red[2], red[3]));
  float ev[4];
  float esum = 0.f;
#pragma unroll
  for (int j = 0; j < 4; j++) {
    int n = j * 256 + t;
    float e = (n < N3) ? __expf(vals[j] - vmax) : 0.f;
    ev[j] = e;
    esum += e;
  }
#pragma unroll
  for (int off = 32; off > 0; off >>= 1) esum += __shfl_xor(esum, off);
  if ((t & 63) == 0) red[4 + wid] = esum;
  __syncthreads();
  esum = red[4] + red[5] + red[6] + red[7];
  float inv = 1.f / esum;
#pragma unroll
  for (int j = 0; j < 4; j++) {
    int n = j * 256 + t;
    if (n < N3) out[(size_t)m * N3 + n] = ev[j] * inv;
  }
}

extern "C" void kernel_launch(void* const* d_in, const int* in_sizes, int n_in,
                              void* d_out, int out_size, void* d_ws, size_t ws_size,
                              hipStream_t stream) {
  const float* x = (const float*)d_in[0];
  const float* filters = (const float*)d_in[1];
  const float* W1 = (const float*)d_in[2];
  const float* b1 = (const float*)d_in[3];
  const float* W2 = (const float*)d_in[4];
  const float* b2 = (const float*)d_in[5];
  const float* Wo = (const float*)d_in[6];
  const float* bo = (const float*)d_in[7];
  float* out = (float*)d_out;

  float* ws = (float*)d_ws;
  float* s = ws;                                    // 64*224*224
  float* flat = s + (size_t)Bsz * HS;               // 64*98568
  float* partial = flat + (size_t)Bsz * FEAT;       // NCH*64*512
  float* h1 = partial + (size_t)NCH * Bsz * N1;     // 64*512
  float* h2 = h1 + (size_t)Bsz * N1;                // 64*256

  k_chsum<<<(Bsz * HS / 4 + 255) / 256, 256, 0, stream>>>((const float4*)x, (float4*)s);
  k_convpool<<<(Bsz * PP + 255) / 256, 256, 0, stream>>>(s, filters, flat);
  dim3 g1(4, NCH);
  k_gemm1<<<g1, 256, 0, stream>>>(flat, W1, partial);
  k_red1<<<(Bsz * N1 + 255) / 256, 256, 0, stream>>>(partial, b1, h1);
  k_gemm2<<<Bsz, 256, 0, stream>>>(h1, W2, b2, h2);
  k_out<<<Bsz, 256, 0, stream>>>(h2, Wo, bo, out);
}

// Round 4
// 245.752 us; speedup vs baseline: 5.1827x; 5.1827x over previous
//
#include <hip/hip_runtime.h>
#include <math.h>

#define Bsz 64
#define Himg 224
#define HS (Himg*Himg)        // 50176
#define PW 111
#define PP (PW*PW)            // 12321
#define Fn 8
#define FEAT (Fn*PP)          // 98568
#define FEATP 98576           // FEAT padded to multiple of 16 (pad zeroed)
#define KT_TOT 6161           // FEATP/16 k-tiles
#define CHUNK_T 24            // k-tiles per split-K chunk (384 k)
#define NCH 257               // ceil(KT_TOT/CHUNK_T)
#define N1 512
#define N2 256
#define N3 1000
#define RG 8                  // red1 k-groups

// async global->LDS, 16B per lane; LDS base wave-uniform, global src per-lane
#define GLOAD_LDS16(g, l)                                                     \
  __builtin_amdgcn_global_load_lds(                                           \
      (const __attribute__((address_space(1))) void*)(g),                     \
      (__attribute__((address_space(3))) void*)(l), 16, 0, 0)

// ---------------- channel sum: s[b,y,x] = sum_c x[b,c,y,x] (float4) --------
__global__ void k_chsum(const float4* __restrict__ x, float4* __restrict__ s) {
  int i = blockIdx.x * 256 + threadIdx.x;
  const int HQ = HS / 4;
  if (i >= Bsz * HQ) return;
  int b = i / HQ, p = i - b * HQ;
  const float4* xb = x + (size_t)b * 3 * HQ + p;
  float4 a = xb[0], c = xb[HQ], d = xb[2 * HQ];
  s[i] = make_float4(a.x + c.x + d.x, a.y + c.y + d.y,
                     a.z + c.z + d.z, a.w + c.w + d.w);
}

// ------------- conv3x3 (8 filt) + relu + maxpool2x2 -> flat (padded) -------
__global__ void k_convpool(const float* __restrict__ s, const float* __restrict__ filt,
                           float* __restrict__ flat) {
  int i = blockIdx.x * 256 + threadIdx.x;
  if (i < Bsz * (FEATP - FEAT))  // zero the 8-float pad of each batch row
    flat[(size_t)(i >> 3) * FEATP + FEAT + (i & 7)] = 0.f;
  if (i >= Bsz * PP) return;
  int b = i / PP, r = i - b * PP;
  int py = r / PW, px = r - py * PW;
  const float* sp = s + (size_t)b * HS + (size_t)(2 * py) * Himg + 2 * px;
  float p[4][4];
#pragma unroll
  for (int dy = 0; dy < 4; dy++)
#pragma unroll
    for (int dx = 0; dx < 4; dx++)
      p[dy][dx] = sp[dy * Himg + dx];
  float* outb = flat + (size_t)b * FEATP + r;
#pragma unroll
  for (int f = 0; f < Fn; f++) {
    float mx = 0.f;
#pragma unroll
    for (int oy = 0; oy < 2; oy++)
#pragma unroll
      for (int ox = 0; ox < 2; ox++) {
        float c = 0.f;
#pragma unroll
        for (int dy = 0; dy < 3; dy++)
#pragma unroll
          for (int dx = 0; dx < 3; dx++)
            c = fmaf(p[oy + dy][ox + dx], filt[f * 9 + dy * 3 + dx], c);
        mx = fmaxf(mx, c);
      }
    outb[(size_t)f * PP] = mx;
  }
}

// ---------------- GEMM1 split-K partials: (64 x K) @ (K x 512) -------------
// grid (4 n-tiles of 128, NCH chunks). Block 64m x 128n, 256 thr, thread 8m x 4n.
// W double-buffered in LDS via global_load_lds; A read from global (L1
// broadcast: 2 distinct 16B addrs per wave-load). One barrier per k-tile.
__global__ void __launch_bounds__(256) k_gemm1(const float* __restrict__ A,
                                               const float* __restrict__ W,
                                               float* __restrict__ partial) {
  __shared__ float Wt[2][16][128];   // 16 KB
  const int t = threadIdx.x;
  const int wv = t >> 6;
  const int lane = t & 63;
  const int col0 = blockIdx.x * 128;
  const int c = blockIdx.y;
  const int t0 = c * CHUNK_T;
  const int nt = min(CHUNK_T, KT_TOT - t0);
  const int mg = t >> 5;             // 8 m-groups of 8 rows
  const int cg = t & 31;             // 32 col-groups of 4 cols
  // W stage source mapping (per lane)
  const int srow = (lane >> 5);          // 0..1
  const int scol = (lane & 31) * 4;

  const float* Abase = A + (size_t)(mg * 8) * FEATP;

  float4 acc[8];
#pragma unroll
  for (int i = 0; i < 8; i++) acc[i] = make_float4(0.f, 0.f, 0.f, 0.f);

  // ---- stage k-tile `kt` (16 rows x 128 cols) into Wt[buf] ----
  // wave wv covers rows 4wv..4wv+3 with two 1KB loads (2 rows each)
#define STAGE_W(buf, kt)                                                      \
  {                                                                           \
    int r0 = (kt) * 16 + wv * 4 + srow;                                       \
    int g0 = min(r0, FEAT - 1);                                               \
    int g1 = min(r0 + 2, FEAT - 1);                                           \
    GLOAD_LDS16(W + (size_t)g0 * N1 + col0 + scol, &Wt[buf][wv * 4][0]);      \
    GLOAD_LDS16(W + (size_t)g1 * N1 + col0 + scol, &Wt[buf][wv * 4 + 2][0]);  \
  }

  STAGE_W(0, t0)
  __syncthreads();

  for (int s = 0; s < nt; s++) {
    const int buf = s & 1;
    if (s + 1 < nt) STAGE_W(buf ^ 1, t0 + s + 1)
    const int k16 = (t0 + s) * 16;
#pragma unroll
    for (int kq = 0; kq < 4; kq++) {
      float4 af0 = *(const float4*)(Abase + 0 * FEATP + k16 + kq * 4);
      float4 af1 = *(const float4*)(Abase + 1 * FEATP + k16 + kq * 4);
      float4 af2 = *(const float4*)(Abase + 2 * FEATP + k16 + kq * 4);
      float4 af3 = *(const float4*)(Abase + 3 * FEATP + k16 + kq * 4);
      float4 af4 = *(const float4*)(Abase + 4 * FEATP + k16 + kq * 4);
      float4 af5 = *(const float4*)(Abase + 5 * FEATP + k16 + kq * 4);
      float4 af6 = *(const float4*)(Abase + 6 * FEATP + k16 + kq * 4);
      float4 af7 = *(const float4*)(Abase + 7 * FEATP + k16 + kq * 4);
#pragma unroll
      for (int kk = 0; kk < 4; kk++) {
        float4 w = *(const float4*)&Wt[buf][kq * 4 + kk][cg * 4];
#define FMA_ROW(idx, af)                                                      \
        {                                                                     \
          float a_ = (kk == 0) ? af.x : (kk == 1) ? af.y                      \
                     : (kk == 2) ? af.z : af.w;                               \
          acc[idx].x = fmaf(a_, w.x, acc[idx].x);                             \
          acc[idx].y = fmaf(a_, w.y, acc[idx].y);                             \
          acc[idx].z = fmaf(a_, w.z, acc[idx].z);                             \
          acc[idx].w = fmaf(a_, w.w, acc[idx].w);                             \
        }
        FMA_ROW(0, af0) FMA_ROW(1, af1) FMA_ROW(2, af2) FMA_ROW(3, af3)
        FMA_ROW(4, af4) FMA_ROW(5, af5) FMA_ROW(6, af6) FMA_ROW(7, af7)
#undef FMA_ROW
      }
    }
    __syncthreads();
  }

  float* pp = partial + ((size_t)c * Bsz + mg * 8) * N1 + col0 + cg * 4;
#pragma unroll
  for (int i = 0; i < 8; i++)
    *(float4*)(pp + (size_t)i * N1) = acc[i];
}

// -------- red1a: partial[257][64][512] -> partial2[8][64*512] --------------
__global__ void k_red1a(const float* __restrict__ partial, float* __restrict__ partial2) {
  int i = blockIdx.x * 256 + threadIdx.x;   // elem 0..32767
  int g = blockIdx.y;
  int c0 = g * 33;
  int c1 = min(c0 + 33, NCH);
  float sum = 0.f;
  for (int c = c0; c < c1; c++) sum += partial[(size_t)c * Bsz * N1 + i];
  partial2[(size_t)g * Bsz * N1 + i] = sum;
}

// -------- red1b: sum 8 groups + bias + relu -> h1 [64,512] -----------------
__global__ void k_red1b(const float* __restrict__ partial2, const float* __restrict__ b1,
                        float* __restrict__ h1) {
  int i = blockIdx.x * 256 + threadIdx.x;
  float sum = 0.f;
#pragma unroll
  for (int g = 0; g < RG; g++) sum += partial2[(size_t)g * Bsz * N1 + i];
  h1[i] = fmaxf(sum + b1[i & (N1 - 1)], 0.f);
}

// -------- GEMM2: h2 = relu(h1 @ W2 + b2). grid 256 = (m, n-quarter) --------
__global__ void __launch_bounds__(256) k_gemm2(const float* __restrict__ h1,
                                               const float* __restrict__ W2,
                                               const float* __restrict__ b2,
                                               float* __restrict__ h2) {
  const int m = blockIdx.x >> 2;
  const int nq = blockIdx.x & 3;
  const int t = threadIdx.x;
  __shared__ float a[N1];
  __shared__ float red[4][64];
  a[t] = h1[(size_t)m * N1 + t];
  a[256 + t] = h1[(size_t)m * N1 + 256 + t];
  __syncthreads();
  const int col = nq * 64 + (t & 63);
  const int ks = (t >> 6) * 128;
  float sum = 0.f;
#pragma unroll 8
  for (int k = 0; k < 128; k++)
    sum = fmaf(a[ks + k], W2[(size_t)(ks + k) * N2 + col], sum);
  red[t >> 6][t & 63] = sum;
  __syncthreads();
  if (t < 64) {
    float tot = red[0][t] + red[1][t] + red[2][t] + red[3][t] + b2[nq * 64 + t];
    h2[(size_t)m * N2 + nq * 64 + t] = fmaxf(tot, 0.f);
  }
}

// -------- logits = h2 @ Wo + bo. grid 256 = (m, n-chunk of 250) ------------
__global__ void __launch_bounds__(256) k_logits(const float* __restrict__ h2,
                                                const float* __restrict__ Wo,
                                                const float* __restrict__ bo,
                                                float* __restrict__ logits) {
  const int m = blockIdx.x >> 2;
  const int nc = blockIdx.x & 3;
  const int t = threadIdx.x;
  __shared__ float a[N2];
  a[t] = h2[(size_t)m * N2 + t];
  __syncthreads();
  const int col = nc * 250 + t;
  if (t >= 250) return;
  float sum = bo[col];
#pragma unroll 8
  for (int k = 0; k < N2; k++)
    sum = fmaf(a[k], Wo[(size_t)k * N3 + col], sum);
  logits[(size_t)m * N3 + col] = sum;
}

// -------- softmax over logits rows -> out ----------------------------------
__global__ void __launch_bounds__(256) k_softmax(const float* __restrict__ logits,
                                                 float* __restrict__ out) {
  const int m = blockIdx.x;
  const int t = threadIdx.x;
  __shared__ float red[8];
  float vals[4];
  float vmax = -3.4e38f;
#pragma unroll
  for (int j = 0; j < 4; j++) {
    int n = j * 256 + t;
    vals[j] = (n < N3) ? logits[(size_t)m * N3 + n] : -3.4e38f;
    vmax = fmaxf(vmax, vals[j]);
  }
#pragma unroll
  for (int off = 32; off > 0; off >>= 1) vmax = fmaxf(vmax, __shfl_xor(vmax, off));
  const int wid = t >> 6;
  if ((t & 63) == 0) red[wid] = vmax;
  __syncthreads();
  vmax = fmaxf(fmaxf(red[0], red[1]), fmaxf(red[2], red[3]));
  float ev[4];
  float esum = 0.f;
#pragma unroll
  for (int j = 0; j < 4; j++) {
    int n = j * 256 + t;
    float e = (n < N3) ? __expf(vals[j] - vmax) : 0.f;
    ev[j] = e;
    esum += e;
  }
#pragma unroll
  for (int off = 32; off > 0; off >>= 1) esum += __shfl_xor(esum, off);
  if ((t & 63) == 0) red[4 + wid] = esum;
  __syncthreads();
  esum = red[4] + red[5] + red[6] + red[7];
  float inv = 1.f / esum;
#pragma unroll
  for (int j = 0; j < 4; j++) {
    int n = j * 256 + t;
    if (n < N3) out[(size_t)m * N3 + n] = ev[j] * inv;
  }
}

extern "C" void kernel_launch(void* const* d_in, const int* in_sizes, int n_in,
                              void* d_out, int out_size, void* d_ws, size_t ws_size,
                              hipStream_t stream) {
  const float* x = (const float*)d_in[0];
  const float* filters = (const float*)d_in[1];
  const float* W1 = (const float*)d_in[2];
  const float* b1 = (const float*)d_in[3];
  const float* W2 = (const float*)d_in[4];
  const float* b2 = (const float*)d_in[5];
  const float* Wo = (const float*)d_in[6];
  const float* bo = (const float*)d_in[7];
  float* out = (float*)d_out;

  float* ws = (float*)d_ws;
  float* s = ws;                                     // 64*50176
  float* flat = s + (size_t)Bsz * HS;                // 64*98576 (padded)
  float* partial = flat + (size_t)Bsz * FEATP;       // 257*64*512
  float* partial2 = partial + (size_t)NCH * Bsz * N1;// 8*64*512
  float* h1 = partial2 + (size_t)RG * Bsz * N1;      // 64*512
  float* h2 = h1 + (size_t)Bsz * N1;                 // 64*256
  float* logits = h2 + (size_t)Bsz * N2;             // 64*1000

  k_chsum<<<(Bsz * HS / 4 + 255) / 256, 256, 0, stream>>>((const float4*)x, (float4*)s);
  k_convpool<<<(Bsz * PP + 255) / 256, 256, 0, stream>>>(s, filters, flat);
  dim3 g1(4, NCH);
  k_gemm1<<<g1, 256, 0, stream>>>(flat, W1, partial);
  dim3 gr(Bsz * N1 / 256, RG);
  k_red1a<<<gr, 256, 0, stream>>>(partial, partial2);
  k_red1b<<<Bsz * N1 / 256, 256, 0, stream>>>(partial2, b1, h1);
  k_gemm2<<<Bsz * 4, 256, 0, stream>>>(h1, W2, b2, h2);
  k_logits<<<Bsz * 4, 256, 0, stream>>>(h2, Wo, bo, logits);
  k_softmax<<<Bsz, 256, 0, stream>>>(logits, out);
}

// Round 5
// 163.173 us; speedup vs baseline: 7.8056x; 1.5061x over previous
//
#include <hip/hip_runtime.h>
#include <math.h>

#define Bsz 64
#define Himg 224
#define HS (Himg*Himg)        // 50176
#define PW 111
#define PP (PW*PW)            // 12321
#define Fn 8
#define FEAT (Fn*PP)          // 98568
#define FEATP 98576           // FEAT padded to multiple of 16 (pad zeroed)
#define KT_TOT 6161           // FEATP/16 k-tiles
#define CHUNK_T 24            // k-tiles per split-K chunk (384 k)
#define NCH 257               // ceil(KT_TOT/CHUNK_T)
#define N1 512
#define N2 256
#define N3 1000
#define RG 8                  // red1 k-groups

// async global->LDS, 16B per lane; LDS base wave-uniform, global src per-lane
#define GLOAD_LDS16(g, l)                                                     \
  __builtin_amdgcn_global_load_lds(                                           \
      (const __attribute__((address_space(1))) void*)(g),                     \
      (__attribute__((address_space(3))) void*)(l), 16, 0, 0)

// ---------------- channel sum: s[b,y,x] = sum_c x[b,c,y,x] (float4) --------
__global__ void k_chsum(const float4* __restrict__ x, float4* __restrict__ s) {
  int i = blockIdx.x * 256 + threadIdx.x;
  const int HQ = HS / 4;
  if (i >= Bsz * HQ) return;
  int b = i / HQ, p = i - b * HQ;
  const float4* xb = x + (size_t)b * 3 * HQ + p;
  float4 a = xb[0], c = xb[HQ], d = xb[2 * HQ];
  s[i] = make_float4(a.x + c.x + d.x, a.y + c.y + d.y,
                     a.z + c.z + d.z, a.w + c.w + d.w);
}

// ------------- conv3x3 (8 filt) + relu + maxpool2x2 -> flat (padded) -------
__global__ void k_convpool(const float* __restrict__ s, const float* __restrict__ filt,
                           float* __restrict__ flat) {
  int i = blockIdx.x * 256 + threadIdx.x;
  if (i < Bsz * (FEATP - FEAT))  // zero the 8-float pad of each batch row
    flat[(size_t)(i >> 3) * FEATP + FEAT + (i & 7)] = 0.f;
  if (i >= Bsz * PP) return;
  int b = i / PP, r = i - b * PP;
  int py = r / PW, px = r - py * PW;
  const float* sp = s + (size_t)b * HS + (size_t)(2 * py) * Himg + 2 * px;
  float p[4][4];
#pragma unroll
  for (int dy = 0; dy < 4; dy++)
#pragma unroll
    for (int dx = 0; dx < 4; dx++)
      p[dy][dx] = sp[dy * Himg + dx];
  float* outb = flat + (size_t)b * FEATP + r;
#pragma unroll
  for (int f = 0; f < Fn; f++) {
    float mx = 0.f;
#pragma unroll
    for (int oy = 0; oy < 2; oy++)
#pragma unroll
      for (int ox = 0; ox < 2; ox++) {
        float c = 0.f;
#pragma unroll
        for (int dy = 0; dy < 3; dy++)
#pragma unroll
          for (int dx = 0; dx < 3; dx++)
            c = fmaf(p[oy + dy][ox + dx], filt[f * 9 + dy * 3 + dx], c);
        mx = fmaxf(mx, c);
      }
    outb[(size_t)f * PP] = mx;
  }
}

// ---------------- GEMM1 split-K partials: (64 x K) @ (K x 512) -------------
// grid (8 n-tiles of 64 cols, NCH k-chunks), block 256 thr (4 waves).
// Block tile 64m x 64n, thread 8m x 2n. BOTH A and W staged direct-to-LDS via
// global_load_lds (2 VMEM instr/wave/k-tile), double-buffered, one barrier
// per k-tile. A read back via wave-broadcast ds_read_b128 (conflict-free).
__global__ void __launch_bounds__(256) k_gemm1(const float* __restrict__ A,
                                               const float* __restrict__ W,
                                               float* __restrict__ partial) {
  __shared__ float Wt[2][16][64];    // [k][n]  4 KB x2
  __shared__ float As[2][64][16];    // [m][k]  4 KB x2
  const int t = threadIdx.x;
  const int wv = t >> 6;
  const int lane = t & 63;
  const int col0 = blockIdx.x * 64;
  const int c = blockIdx.y;
  const int t0 = c * CHUNK_T;
  const int nt = min(CHUNK_T, KT_TOT - t0);
  const int mg = t >> 5;             // 8 m-groups of 8 rows
  const int cg = t & 31;             // 32 col-groups of 2 cols
  // W staging: wave wv covers k-rows 4wv..4wv+3; lane -> row wv*4+(l>>4), col (l&15)*4
  const int wsrow = lane >> 4;
  const int wscol = (lane & 15) * 4;
  // A staging: wave wv covers m-rows 16wv..16wv+15; lane -> row wv*16+(l>>2), k (l&3)*4
  const float* Asrc = A + (size_t)(wv * 16 + (lane >> 2)) * FEATP + (lane & 3) * 4;

#define STAGE(buf, kt)                                                        \
  {                                                                           \
    int wr = min((kt) * 16 + wv * 4 + wsrow, FEAT - 1);                       \
    GLOAD_LDS16(W + (size_t)wr * N1 + col0 + wscol, &Wt[buf][wv * 4][0]);     \
    GLOAD_LDS16(Asrc + (size_t)(kt) * 16, &As[buf][wv * 16][0]);              \
  }

  float2 acc[8];
#pragma unroll
  for (int i = 0; i < 8; i++) acc[i] = make_float2(0.f, 0.f);

  STAGE(0, t0)
  __syncthreads();

  for (int s = 0; s < nt; s++) {
    const int buf = s & 1;
    if (s + 1 < nt) STAGE(buf ^ 1, t0 + s + 1)
#pragma unroll
    for (int kq = 0; kq < 4; kq++) {
      float2 w0 = *(const float2*)&Wt[buf][kq * 4 + 0][cg * 2];
      float2 w1 = *(const float2*)&Wt[buf][kq * 4 + 1][cg * 2];
      float2 w2 = *(const float2*)&Wt[buf][kq * 4 + 2][cg * 2];
      float2 w3 = *(const float2*)&Wt[buf][kq * 4 + 3][cg * 2];
#pragma unroll
      for (int r = 0; r < 8; r++) {
        float4 a = *(const float4*)&As[buf][mg * 8 + r][kq * 4];
        acc[r].x = fmaf(a.x, w0.x, acc[r].x);
        acc[r].y = fmaf(a.x, w0.y, acc[r].y);
        acc[r].x = fmaf(a.y, w1.x, acc[r].x);
        acc[r].y = fmaf(a.y, w1.y, acc[r].y);
        acc[r].x = fmaf(a.z, w2.x, acc[r].x);
        acc[r].y = fmaf(a.z, w2.y, acc[r].y);
        acc[r].x = fmaf(a.w, w3.x, acc[r].x);
        acc[r].y = fmaf(a.w, w3.y, acc[r].y);
      }
    }
    __syncthreads();
  }

  float* pp = partial + ((size_t)c * Bsz + mg * 8) * N1 + col0 + cg * 2;
#pragma unroll
  for (int i = 0; i < 8; i++)
    *(float2*)(pp + (size_t)i * N1) = acc[i];
}

// -------- red1a: partial[257][64][512] -> partial2[8][64*512] --------------
__global__ void k_red1a(const float* __restrict__ partial, float* __restrict__ partial2) {
  int i = blockIdx.x * 256 + threadIdx.x;   // elem 0..32767
  int g = blockIdx.y;
  int c0 = g * 33;
  int c1 = min(c0 + 33, NCH);
  float sum = 0.f;
  for (int c = c0; c < c1; c++) sum += partial[(size_t)c * Bsz * N1 + i];
  partial2[(size_t)g * Bsz * N1 + i] = sum;
}

// -------- red1b: sum 8 groups + bias + relu -> h1 [64,512] -----------------
__global__ void k_red1b(const float* __restrict__ partial2, const float* __restrict__ b1,
                        float* __restrict__ h1) {
  int i = blockIdx.x * 256 + threadIdx.x;
  float sum = 0.f;
#pragma unroll
  for (int g = 0; g < RG; g++) sum += partial2[(size_t)g * Bsz * N1 + i];
  h1[i] = fmaxf(sum + b1[i & (N1 - 1)], 0.f);
}

// -------- GEMM2: h2 = relu(h1 @ W2 + b2). grid 256 = (m, n-quarter) --------
__global__ void __launch_bounds__(256) k_gemm2(const float* __restrict__ h1,
                                               const float* __restrict__ W2,
                                               const float* __restrict__ b2,
                                               float* __restrict__ h2) {
  const int m = blockIdx.x >> 2;
  const int nq = blockIdx.x & 3;
  const int t = threadIdx.x;
  __shared__ float a[N1];
  __shared__ float red[4][64];
  a[t] = h1[(size_t)m * N1 + t];
  a[256 + t] = h1[(size_t)m * N1 + 256 + t];
  __syncthreads();
  const int col = nq * 64 + (t & 63);
  const int ks = (t >> 6) * 128;
  float sum = 0.f;
#pragma unroll 8
  for (int k = 0; k < 128; k++)
    sum = fmaf(a[ks + k], W2[(size_t)(ks + k) * N2 + col], sum);
  red[t >> 6][t & 63] = sum;
  __syncthreads();
  if (t < 64) {
    float tot = red[0][t] + red[1][t] + red[2][t] + red[3][t] + b2[nq * 64 + t];
    h2[(size_t)m * N2 + nq * 64 + t] = fmaxf(tot, 0.f);
  }
}

// -------- logits = h2 @ Wo + bo. grid 256 = (m, n-chunk of 250) ------------
__global__ void __launch_bounds__(256) k_logits(const float* __restrict__ h2,
                                                const float* __restrict__ Wo,
                                                const float* __restrict__ bo,
                                                float* __restrict__ logits) {
  const int m = blockIdx.x >> 2;
  const int nc = blockIdx.x & 3;
  const int t = threadIdx.x;
  __shared__ float a[N2];
  a[t] = h2[(size_t)m * N2 + t];
  __syncthreads();
  const int col = nc * 250 + t;
  if (t >= 250) return;
  float sum = bo[col];
#pragma unroll 8
  for (int k = 0; k < N2; k++)
    sum = fmaf(a[k], Wo[(size_t)k * N3 + col], sum);
  logits[(size_t)m * N3 + col] = sum;
}

// -------- softmax over logits rows -> out ----------------------------------
__global__ void __launch_bounds__(256) k_softmax(const float* __restrict__ logits,
                                                 float* __restrict__ out) {
  const int m = blockIdx.x;
  const int t = threadIdx.x;
  __shared__ float red[8];
  float vals[4];
  float vmax = -3.4e38f;
#pragma unroll
  for (int j = 0; j < 4; j++) {
    int n = j * 256 + t;
    vals[j] = (n < N3) ? logits[(size_t)m * N3 + n] : -3.4e38f;
    vmax = fmaxf(vmax, vals[j]);
  }
#pragma unroll
  for (int off = 32; off > 0; off >>= 1) vmax = fmaxf(vmax, __shfl_xor(vmax, off));
  const int wid = t >> 6;
  if ((t & 63) == 0) red[wid] = vmax;
  __syncthreads();
  vmax = fmaxf(fmaxf(red[0], red[1]), fmaxf(red[2], red[3]));
  float ev[4];
  float esum = 0.f;
#pragma unroll
  for (int j = 0; j < 4; j++) {
    int n = j * 256 + t;
    float e = (n < N3) ? __expf(vals[j] - vmax) : 0.f;
    ev[j] = e;
    esum += e;
  }
#pragma unroll
  for (int off = 32; off > 0; off >>= 1) esum += __shfl_xor(esum, off);
  if ((t & 63) == 0) red[4 + wid] = esum;
  __syncthreads();
  esum = red[4] + red[5] + red[6] + red[7];
  float inv = 1.f / esum;
#pragma unroll
  for (int j = 0; j < 4; j++) {
    int n = j * 256 + t;
    if (n < N3) out[(size_t)m * N3 + n] = ev[j] * inv;
  }
}

extern "C" void kernel_launch(void* const* d_in, const int* in_sizes, int n_in,
                              void* d_out, int out_size, void* d_ws, size_t ws_size,
                              hipStream_t stream) {
  const float* x = (const float*)d_in[0];
  const float* filters = (const float*)d_in[1];
  const float* W1 = (const float*)d_in[2];
  const float* b1 = (const float*)d_in[3];
  const float* W2 = (const float*)d_in[4];
  const float* b2 = (const float*)d_in[5];
  const float* Wo = (const float*)d_in[6];
  const float* bo = (const float*)d_in[7];
  float* out = (float*)d_out;

  float* ws = (float*)d_ws;
  float* s = ws;                                     // 64*50176
  float* flat = s + (size_t)Bsz * HS;                // 64*98576 (padded)
  float* partial = flat + (size_t)Bsz * FEATP;       // 257*64*512
  float* partial2 = partial + (size_t)NCH * Bsz * N1;// 8*64*512
  float* h1 = partial2 + (size_t)RG * Bsz * N1;      // 64*512
  float* h2 = h1 + (size_t)Bsz * N1;                 // 64*256
  float* logits = h2 + (size_t)Bsz * N2;             // 64*1000

  k_chsum<<<(Bsz * HS / 4 + 255) / 256, 256, 0, stream>>>((const float4*)x, (float4*)s);
  k_convpool<<<(Bsz * PP + 255) / 256, 256, 0, stream>>>(s, filters, flat);
  dim3 g1(8, NCH);
  k_gemm1<<<g1, 256, 0, stream>>>(flat, W1, partial);
  dim3 gr(Bsz * N1 / 256, RG);
  k_red1a<<<gr, 256, 0, stream>>>(partial, partial2);
  k_red1b<<<Bsz * N1 / 256, 256, 0, stream>>>(partial2, b1, h1);
  k_gemm2<<<Bsz * 4, 256, 0, stream>>>(h1, W2, b2, h2);
  k_logits<<<Bsz * 4, 256, 0, stream>>>(h2, Wo, bo, logits);
  k_softmax<<<Bsz, 256, 0, stream>>>(logits, out);
}

// Round 6
// 152.603 us; speedup vs baseline: 8.3463x; 1.0693x over previous
//
#include <hip/hip_runtime.h>
#include <math.h>

#define Bsz 64
#define Himg 224
#define HS (Himg*Himg)        // 50176
#define PW 111
#define PP (PW*PW)            // 12321
#define Fn 8
#define FEAT (Fn*PP)          // 98568
#define FEATP 98576           // FEAT padded to multiple of 16 (pad zeroed)
#define KT_TOT 6161           // FEATP/16 k-tiles
#define CHUNK_T 24            // k-tiles per split-K chunk (384 k)
#define NCH 257               // ceil(KT_TOT/CHUNK_T)
#define N1 512
#define N2 256
#define N3 1000
#define RG 8                  // red1 k-groups

// async global->LDS, 16B per lane; LDS base wave-uniform, global src per-lane
#define GLOAD_LDS16(g, l)                                                     \
  __builtin_amdgcn_global_load_lds(                                           \
      (const __attribute__((address_space(1))) void*)(g),                     \
      (__attribute__((address_space(3))) void*)(l), 16, 0, 0)

// ---------------- channel sum: s[b,y,x] = sum_c x[b,c,y,x] (float4) --------
__global__ void k_chsum(const float4* __restrict__ x, float4* __restrict__ s) {
  int i = blockIdx.x * 256 + threadIdx.x;
  const int HQ = HS / 4;
  if (i >= Bsz * HQ) return;
  int b = i / HQ, p = i - b * HQ;
  const float4* xb = x + (size_t)b * 3 * HQ + p;
  float4 a = xb[0], c = xb[HQ], d = xb[2 * HQ];
  s[i] = make_float4(a.x + c.x + d.x, a.y + c.y + d.y,
                     a.z + c.z + d.z, a.w + c.w + d.w);
}

// ------------- conv3x3 (8 filt) + relu + maxpool2x2 -> flat (padded) -------
__global__ void k_convpool(const float* __restrict__ s, const float* __restrict__ filt,
                           float* __restrict__ flat) {
  int i = blockIdx.x * 256 + threadIdx.x;
  if (i < Bsz * (FEATP - FEAT))  // zero the 8-float pad of each batch row
    flat[(size_t)(i >> 3) * FEATP + FEAT + (i & 7)] = 0.f;
  if (i >= Bsz * PP) return;
  int b = i / PP, r = i - b * PP;
  int py = r / PW, px = r - py * PW;
  const float* sp = s + (size_t)b * HS + (size_t)(2 * py) * Himg + 2 * px;
  float p[4][4];
#pragma unroll
  for (int dy = 0; dy < 4; dy++)
#pragma unroll
    for (int dx = 0; dx < 4; dx++)
      p[dy][dx] = sp[dy * Himg + dx];
  float* outb = flat + (size_t)b * FEATP + r;
#pragma unroll
  for (int f = 0; f < Fn; f++) {
    float mx = 0.f;
#pragma unroll
    for (int oy = 0; oy < 2; oy++)
#pragma unroll
      for (int ox = 0; ox < 2; ox++) {
        float c = 0.f;
#pragma unroll
        for (int dy = 0; dy < 3; dy++)
#pragma unroll
          for (int dx = 0; dx < 3; dx++)
            c = fmaf(p[oy + dy][ox + dx], filt[f * 9 + dy * 3 + dx], c);
        mx = fmaxf(mx, c);
      }
    outb[(size_t)f * PP] = mx;
  }
}

// ---------------- GEMM1 split-K partials: (64 x K) @ (K x 512) -------------
// grid (4 n-tiles of 128 cols, NCH k-chunks), block 256 thr (4 waves).
// Block tile 64m x 128n, thread 8m x 4n. BOTH A and W staged direct-to-LDS
// via global_load_lds (3 VMEM instr/wave/k-tile), double-buffered, one
// barrier per k-tile. A read back via 32-lane-broadcast ds_read_b128.
__global__ void __launch_bounds__(256) k_gemm1(const float* __restrict__ A,
                                               const float* __restrict__ W,
                                               float* __restrict__ partial) {
  __shared__ float Wt[2][16][128];   // [k][n]  8 KB x2
  __shared__ float As[2][64][16];    // [m][k]  4 KB x2
  const int t = threadIdx.x;
  const int wv = t >> 6;
  const int lane = t & 63;
  const int col0 = blockIdx.x * 128;
  const int c = blockIdx.y;
  const int t0 = c * CHUNK_T;
  const int nt = min(CHUNK_T, KT_TOT - t0);
  const int mg = t >> 5;             // 8 m-groups of 8 rows
  const int cg = t & 31;             // 32 col-groups of 4 cols
  // W staging: wave wv covers k-rows 4wv..4wv+3; 2 loads of 2 rows each
  const int wsrow = lane >> 5;           // 0..1
  const int wscol = (lane & 31) * 4;
  // A staging: wave wv covers m-rows 16wv..16wv+15 (one 1KB load)
  const float* Asrc = A + (size_t)(wv * 16 + (lane >> 2)) * FEATP + (lane & 3) * 4;

#define STAGE(buf, kt)                                                        \
  {                                                                           \
    int r0 = (kt) * 16 + wv * 4 + wsrow;                                      \
    int g0 = min(r0, FEAT - 1);                                               \
    int g1 = min(r0 + 2, FEAT - 1);                                           \
    GLOAD_LDS16(W + (size_t)g0 * N1 + col0 + wscol, &Wt[buf][wv * 4][0]);     \
    GLOAD_LDS16(W + (size_t)g1 * N1 + col0 + wscol, &Wt[buf][wv * 4 + 2][0]); \
    GLOAD_LDS16(Asrc + (size_t)(kt) * 16, &As[buf][wv * 16][0]);              \
  }

  float4 acc[8];
#pragma unroll
  for (int i = 0; i < 8; i++) acc[i] = make_float4(0.f, 0.f, 0.f, 0.f);

  STAGE(0, t0)
  __syncthreads();

  for (int s = 0; s < nt; s++) {
    const int buf = s & 1;
    if (s + 1 < nt) STAGE(buf ^ 1, t0 + s + 1)
#pragma unroll
    for (int kq = 0; kq < 4; kq++) {
      float4 w0 = *(const float4*)&Wt[buf][kq * 4 + 0][cg * 4];
      float4 w1 = *(const float4*)&Wt[buf][kq * 4 + 1][cg * 4];
      float4 w2 = *(const float4*)&Wt[buf][kq * 4 + 2][cg * 4];
      float4 w3 = *(const float4*)&Wt[buf][kq * 4 + 3][cg * 4];
#pragma unroll
      for (int r = 0; r < 8; r++) {
        float4 a = *(const float4*)&As[buf][mg * 8 + r][kq * 4];
        acc[r].x = fmaf(a.x, w0.x, acc[r].x);
        acc[r].y = fmaf(a.x, w0.y, acc[r].y);
        acc[r].z = fmaf(a.x, w0.z, acc[r].z);
        acc[r].w = fmaf(a.x, w0.w, acc[r].w);
        acc[r].x = fmaf(a.y, w1.x, acc[r].x);
        acc[r].y = fmaf(a.y, w1.y, acc[r].y);
        acc[r].z = fmaf(a.y, w1.z, acc[r].z);
        acc[r].w = fmaf(a.y, w1.w, acc[r].w);
        acc[r].x = fmaf(a.z, w2.x, acc[r].x);
        acc[r].y = fmaf(a.z, w2.y, acc[r].y);
        acc[r].z = fmaf(a.z, w2.z, acc[r].z);
        acc[r].w = fmaf(a.z, w2.w, acc[r].w);
        acc[r].x = fmaf(a.w, w3.x, acc[r].x);
        acc[r].y = fmaf(a.w, w3.y, acc[r].y);
        acc[r].z = fmaf(a.w, w3.z, acc[r].z);
        acc[r].w = fmaf(a.w, w3.w, acc[r].w);
      }
    }
    __syncthreads();
  }

  float* pp = partial + ((size_t)c * Bsz + mg * 8) * N1 + col0 + cg * 4;
#pragma unroll
  for (int i = 0; i < 8; i++)
    *(float4*)(pp + (size_t)i * N1) = acc[i];
}

// -------- red1a: partial[257][64][512] -> partial2[8][64*512] --------------
__global__ void k_red1a(const float* __restrict__ partial, float* __restrict__ partial2) {
  int i = blockIdx.x * 256 + threadIdx.x;   // elem 0..32767
  int g = blockIdx.y;
  int c0 = g * 33;
  int c1 = min(c0 + 33, NCH);
  float sum = 0.f;
  for (int c = c0; c < c1; c++) sum += partial[(size_t)c * Bsz * N1 + i];
  partial2[(size_t)g * Bsz * N1 + i] = sum;
}

// -------- red1b: sum 8 groups + bias + relu -> h1 [64,512] -----------------
__global__ void k_red1b(const float* __restrict__ partial2, const float* __restrict__ b1,
                        float* __restrict__ h1) {
  int i = blockIdx.x * 256 + threadIdx.x;
  float sum = 0.f;
#pragma unroll
  for (int g = 0; g < RG; g++) sum += partial2[(size_t)g * Bsz * N1 + i];
  h1[i] = fmaxf(sum + b1[i & (N1 - 1)], 0.f);
}

// -------- GEMM2: h2 = relu(h1 @ W2 + b2). grid 256 = (m, n-quarter) --------
__global__ void __launch_bounds__(256) k_gemm2(const float* __restrict__ h1,
                                               const float* __restrict__ W2,
                                               const float* __restrict__ b2,
                                               float* __restrict__ h2) {
  const int m = blockIdx.x >> 2;
  const int nq = blockIdx.x & 3;
  const int t = threadIdx.x;
  __shared__ float a[N1];
  __shared__ float red[4][64];
  a[t] = h1[(size_t)m * N1 + t];
  a[256 + t] = h1[(size_t)m * N1 + 256 + t];
  __syncthreads();
  const int col = nq * 64 + (t & 63);
  const int ks = (t >> 6) * 128;
  float sum = 0.f;
#pragma unroll 8
  for (int k = 0; k < 128; k++)
    sum = fmaf(a[ks + k], W2[(size_t)(ks + k) * N2 + col], sum);
  red[t >> 6][t & 63] = sum;
  __syncthreads();
  if (t < 64) {
    float tot = red[0][t] + red[1][t] + red[2][t] + red[3][t] + b2[nq * 64 + t];
    h2[(size_t)m * N2 + nq * 64 + t] = fmaxf(tot, 0.f);
  }
}

// -------- logits = h2 @ Wo + bo. grid 256 = (m, n-chunk of 250) ------------
__global__ void __launch_bounds__(256) k_logits(const float* __restrict__ h2,
                                                const float* __restrict__ Wo,
                                                const float* __restrict__ bo,
                                                float* __restrict__ logits) {
  const int m = blockIdx.x >> 2;
  const int nc = blockIdx.x & 3;
  const int t = threadIdx.x;
  __shared__ float a[N2];
  a[t] = h2[(size_t)m * N2 + t];
  __syncthreads();
  const int col = nc * 250 + t;
  if (t >= 250) return;
  float sum = bo[col];
#pragma unroll 8
  for (int k = 0; k < N2; k++)
    sum = fmaf(a[k], Wo[(size_t)k * N3 + col], sum);
  logits[(size_t)m * N3 + col] = sum;
}

// -------- softmax over logits rows -> out ----------------------------------
__global__ void __launch_bounds__(256) k_softmax(const float* __restrict__ logits,
                                                 float* __restrict__ out) {
  const int m = blockIdx.x;
  const int t = threadIdx.x;
  __shared__ float red[8];
  float vals[4];
  float vmax = -3.4e38f;
#pragma unroll
  for (int j = 0; j < 4; j++) {
    int n = j * 256 + t;
    vals[j] = (n < N3) ? logits[(size_t)m * N3 + n] : -3.4e38f;
    vmax = fmaxf(vmax, vals[j]);
  }
#pragma unroll
  for (int off = 32; off > 0; off >>= 1) vmax = fmaxf(vmax, __shfl_xor(vmax, off));
  const int wid = t >> 6;
  if ((t & 63) == 0) red[wid] = vmax;
  __syncthreads();
  vmax = fmaxf(fmaxf(red[0], red[1]), fmaxf(red[2], red[3]));
  float ev[4];
  float esum = 0.f;
#pragma unroll
  for (int j = 0; j < 4; j++) {
    int n = j * 256 + t;
    float e = (n < N3) ? __expf(vals[j] - vmax) : 0.f;
    ev[j] = e;
    esum += e;
  }
#pragma unroll
  for (int off = 32; off > 0; off >>= 1) esum += __shfl_xor(esum, off);
  if ((t & 63) == 0) red[4 + wid] = esum;
  __syncthreads();
  esum = red[4] + red[5] + red[6] + red[7];
  float inv = 1.f / esum;
#pragma unroll
  for (int j = 0; j < 4; j++) {
    int n = j * 256 + t;
    if (n < N3) out[(size_t)m * N3 + n] = ev[j] * inv;
  }
}

extern "C" void kernel_launch(void* const* d_in, const int* in_sizes, int n_in,
                              void* d_out, int out_size, void* d_ws, size_t ws_size,
                              hipStream_t stream) {
  const float* x = (const float*)d_in[0];
  const float* filters = (const float*)d_in[1];
  const float* W1 = (const float*)d_in[2];
  const float* b1 = (const float*)d_in[3];
  const float* W2 = (const float*)d_in[4];
  const float* b2 = (const float*)d_in[5];
  const float* Wo = (const float*)d_in[6];
  const float* bo = (const float*)d_in[7];
  float* out = (float*)d_out;

  float* ws = (float*)d_ws;
  float* s = ws;                                     // 64*50176
  float* flat = s + (size_t)Bsz * HS;                // 64*98576 (padded)
  float* partial = flat + (size_t)Bsz * FEATP;       // 257*64*512
  float* partial2 = partial + (size_t)NCH * Bsz * N1;// 8*64*512
  float* h1 = partial2 + (size_t)RG * Bsz * N1;      // 64*512
  float* h2 = h1 + (size_t)Bsz * N1;                 // 64*256
  float* logits = h2 + (size_t)Bsz * N2;             // 64*1000

  k_chsum<<<(Bsz * HS / 4 + 255) / 256, 256, 0, stream>>>((const float4*)x, (float4*)s);
  k_convpool<<<(Bsz * PP + 255) / 256, 256, 0, stream>>>(s, filters, flat);
  dim3 g1(4, NCH);
  k_gemm1<<<g1, 256, 0, stream>>>(flat, W1, partial);
  dim3 gr(Bsz * N1 / 256, RG);
  k_red1a<<<gr, 256, 0, stream>>>(partial, partial2);
  k_red1b<<<Bsz * N1 / 256, 256, 0, stream>>>(partial2, b1, h1);
  k_gemm2<<<Bsz * 4, 256, 0, stream>>>(h1, W2, b2, h2);
  k_logits<<<Bsz * 4, 256, 0, stream>>>(h2, Wo, bo, logits);
  k_softmax<<<Bsz, 256, 0, stream>>>(logits, out);
}

// Round 7
// 142.360 us; speedup vs baseline: 8.9468x; 1.0719x over previous
//
#include <hip/hip_runtime.h>
#include <math.h>

#define Bsz 64
#define Himg 224
#define HS (Himg*Himg)        // 50176
#define PW 111
#define PP (PW*PW)            // 12321
#define Fn 8
#define FEAT (Fn*PP)          // 98568
#define FEATP 98592           // FEAT padded to multiple of 32 (pad zeroed)
#define NT32_TOT 3081         // FEATP/32 k-tiles
#define KT32 12               // k32-tiles per split-K chunk (384 k)
#define NCH 257               // ceil(NT32_TOT/KT32)
#define N1 512
#define N2 256
#define N3 1000
#define RG 8                  // red1 k-groups

typedef short short8 __attribute__((ext_vector_type(8)));
typedef float f32x4 __attribute__((ext_vector_type(4)));

// split-float: x = hi + lo (both bf16, truncation split)
__device__ __forceinline__ void cvt_hilo(const float* v, short8& hi, short8& lo) {
#pragma unroll
  for (int j = 0; j < 8; j++) {
    unsigned u = __builtin_bit_cast(unsigned, v[j]);
    hi[j] = (short)(u >> 16);
    float hf = __builtin_bit_cast(float, u & 0xFFFF0000u);
    float r = v[j] - hf;
    lo[j] = (short)(__builtin_bit_cast(unsigned, r) >> 16);
  }
}

// ---------------- channel sum: s[b,y,x] = sum_c x[b,c,y,x] (float4) --------
__global__ void k_chsum(const float4* __restrict__ x, float4* __restrict__ s) {
  int i = blockIdx.x * 256 + threadIdx.x;
  const int HQ = HS / 4;
  if (i >= Bsz * HQ) return;
  int b = i / HQ, p = i - b * HQ;
  const float4* xb = x + (size_t)b * 3 * HQ + p;
  float4 a = xb[0], c = xb[HQ], d = xb[2 * HQ];
  s[i] = make_float4(a.x + c.x + d.x, a.y + c.y + d.y,
                     a.z + c.z + d.z, a.w + c.w + d.w);
}

// ------------- conv3x3 (8 filt) + relu + maxpool2x2 -> flat (padded) -------
__global__ void k_convpool(const float* __restrict__ s, const float* __restrict__ filt,
                           float* __restrict__ flat) {
  int i = blockIdx.x * 256 + threadIdx.x;
  if (i < Bsz * (FEATP - FEAT))  // zero the 24-float pad of each batch row
    flat[(size_t)(i / 24) * FEATP + FEAT + (i % 24)] = 0.f;
  if (i >= Bsz * PP) return;
  int b = i / PP, r = i - b * PP;
  int py = r / PW, px = r - py * PW;
  const float* sp = s + (size_t)b * HS + (size_t)(2 * py) * Himg + 2 * px;
  float p[4][4];
#pragma unroll
  for (int dy = 0; dy < 4; dy++)
#pragma unroll
    for (int dx = 0; dx < 4; dx++)
      p[dy][dx] = sp[dy * Himg + dx];
  float* outb = flat + (size_t)b * FEATP + r;
#pragma unroll
  for (int f = 0; f < Fn; f++) {
    float mx = 0.f;
#pragma unroll
    for (int oy = 0; oy < 2; oy++)
#pragma unroll
      for (int ox = 0; ox < 2; ox++) {
        float c = 0.f;
#pragma unroll
        for (int dy = 0; dy < 3; dy++)
#pragma unroll
          for (int dx = 0; dx < 3; dx++)
            c = fmaf(p[oy + dy][ox + dx], filt[f * 9 + dy * 3 + dx], c);
        mx = fmaxf(mx, c);
      }
    outb[(size_t)f * PP] = mx;
  }
}

// ---------------- GEMM1 split-K via bf16 hi/lo MFMA ------------------------
// C = A(64 x K) @ W(K x 512), split-float: Ahi*Whi + Ahi*Wlo + Alo*Whi.
// grid (4 n-tiles of 128 cols, NCH k-chunks), block 256 thr = 4 waves.
// Wave w owns cols [blk*128 + w*32, +32): 4 m-frags x 2 n-frags of
// mfma_f32_16x16x32_bf16. No LDS, no barriers: frags loaded from global.
// Layouts: A row=lane&15, k=8*(lane>>4)+j; B col=lane&15, same k;
//          D col=lane&15, row=4*(lane>>4)+reg  (m89-verified).
__global__ void __launch_bounds__(256) k_gemm1(const float* __restrict__ A,
                                               const float* __restrict__ W,
                                               float* __restrict__ partial) {
  const int t = threadIdx.x;
  const int w = t >> 6;
  const int lane = t & 63;
  const int col0 = blockIdx.x * 128 + w * 32;
  const int c = blockIdx.y;
  const int tile0 = c * KT32;
  const int nt = min(KT32, NT32_TOT - tile0);
  const int lrow = lane & 15;    // A row / B,D col within frag
  const int lg8 = (lane >> 4) * 8;

  f32x4 acc[4][2];
#pragma unroll
  for (int mf = 0; mf < 4; mf++)
#pragma unroll
    for (int nf = 0; nf < 2; nf++)
#pragma unroll
      for (int r = 0; r < 4; r++) acc[mf][nf][r] = 0.f;

  const float* Arow = A + (size_t)lrow * FEATP + lg8;
  const float* Wcol = W + col0 + lrow;

  for (int s = 0; s < nt; s++) {
    const int k0 = (tile0 + s) * 32;
    // ---- B fragments (W columns), hi/lo ----
    short8 bhi[2], blo[2];
    float bv0[8], bv1[8];
#pragma unroll
    for (int j = 0; j < 8; j++) {
      int kk = k0 + lg8 + j;
      kk = kk < FEAT ? kk : FEAT - 1;   // pad rows: A is 0 there anyway
      const float* wp = Wcol + (size_t)kk * N1;
      bv0[j] = wp[0];
      bv1[j] = wp[16];
    }
    cvt_hilo(bv0, bhi[0], blo[0]);
    cvt_hilo(bv1, bhi[1], blo[1]);
    // ---- A fragments + MFMA ----
#pragma unroll
    for (int mf = 0; mf < 4; mf++) {
      float av[8];
      *(float4*)(av + 0) = *(const float4*)(Arow + (size_t)(mf * 16) * FEATP + k0);
      *(float4*)(av + 4) = *(const float4*)(Arow + (size_t)(mf * 16) * FEATP + k0 + 4);
      short8 ahi, alo;
      cvt_hilo(av, ahi, alo);
#pragma unroll
      for (int nf = 0; nf < 2; nf++) {
        acc[mf][nf] = __builtin_amdgcn_mfma_f32_16x16x32_bf16(ahi, bhi[nf], acc[mf][nf], 0, 0, 0);
        acc[mf][nf] = __builtin_amdgcn_mfma_f32_16x16x32_bf16(ahi, blo[nf], acc[mf][nf], 0, 0, 0);
        acc[mf][nf] = __builtin_amdgcn_mfma_f32_16x16x32_bf16(alo, bhi[nf], acc[mf][nf], 0, 0, 0);
      }
    }
  }

  const int drow = (lane >> 4) * 4;
#pragma unroll
  for (int mf = 0; mf < 4; mf++) {
#pragma unroll
    for (int nf = 0; nf < 2; nf++) {
      float* pp = partial + ((size_t)c * Bsz + mf * 16 + drow) * N1 + col0 + nf * 16 + lrow;
#pragma unroll
      for (int r = 0; r < 4; r++) pp[(size_t)r * N1] = acc[mf][nf][r];
    }
  }
}

// -------- red1a: partial[257][64][512] -> partial2[8][64*512] --------------
__global__ void k_red1a(const float* __restrict__ partial, float* __restrict__ partial2) {
  int i = blockIdx.x * 256 + threadIdx.x;   // elem 0..32767
  int g = blockIdx.y;
  int c0 = g * 33;
  int c1 = min(c0 + 33, NCH);
  float sum = 0.f;
  for (int c = c0; c < c1; c++) sum += partial[(size_t)c * Bsz * N1 + i];
  partial2[(size_t)g * Bsz * N1 + i] = sum;
}

// -------- red1b: sum 8 groups + bias + relu -> h1 [64,512] -----------------
__global__ void k_red1b(const float* __restrict__ partial2, const float* __restrict__ b1,
                        float* __restrict__ h1) {
  int i = blockIdx.x * 256 + threadIdx.x;
  float sum = 0.f;
#pragma unroll
  for (int g = 0; g < RG; g++) sum += partial2[(size_t)g * Bsz * N1 + i];
  h1[i] = fmaxf(sum + b1[i & (N1 - 1)], 0.f);
}

// -------- GEMM2: h2 = relu(h1 @ W2 + b2). grid 256 = (m, n-quarter) --------
__global__ void __launch_bounds__(256) k_gemm2(const float* __restrict__ h1,
                                               const float* __restrict__ W2,
                                               const float* __restrict__ b2,
                                               float* __restrict__ h2) {
  const int m = blockIdx.x >> 2;
  const int nq = blockIdx.x & 3;
  const int t = threadIdx.x;
  __shared__ float a[N1];
  __shared__ float red[4][64];
  a[t] = h1[(size_t)m * N1 + t];
  a[256 + t] = h1[(size_t)m * N1 + 256 + t];
  __syncthreads();
  const int col = nq * 64 + (t & 63);
  const int ks = (t >> 6) * 128;
  float sum = 0.f;
#pragma unroll 8
  for (int k = 0; k < 128; k++)
    sum = fmaf(a[ks + k], W2[(size_t)(ks + k) * N2 + col], sum);
  red[t >> 6][t & 63] = sum;
  __syncthreads();
  if (t < 64) {
    float tot = red[0][t] + red[1][t] + red[2][t] + red[3][t] + b2[nq * 64 + t];
    h2[(size_t)m * N2 + nq * 64 + t] = fmaxf(tot, 0.f);
  }
}

// -------- logits = h2 @ Wo + bo. grid 256 = (m, n-chunk of 250) ------------
__global__ void __launch_bounds__(256) k_logits(const float* __restrict__ h2,
                                                const float* __restrict__ Wo,
                                                const float* __restrict__ bo,
                                                float* __restrict__ logits) {
  const int m = blockIdx.x >> 2;
  const int nc = blockIdx.x & 3;
  const int t = threadIdx.x;
  __shared__ float a[N2];
  a[t] = h2[(size_t)m * N2 + t];
  __syncthreads();
  const int col = nc * 250 + t;
  if (t >= 250) return;
  float sum = bo[col];
#pragma unroll 8
  for (int k = 0; k < N2; k++)
    sum = fmaf(a[k], Wo[(size_t)k * N3 + col], sum);
  logits[(size_t)m * N3 + col] = sum;
}

// -------- softmax over logits rows -> out ----------------------------------
__global__ void __launch_bounds__(256) k_softmax(const float* __restrict__ logits,
                                                 float* __restrict__ out) {
  const int m = blockIdx.x;
  const int t = threadIdx.x;
  __shared__ float red[8];
  float vals[4];
  float vmax = -3.4e38f;
#pragma unroll
  for (int j = 0; j < 4; j++) {
    int n = j * 256 + t;
    vals[j] = (n < N3) ? logits[(size_t)m * N3 + n] : -3.4e38f;
    vmax = fmaxf(vmax, vals[j]);
  }
#pragma unroll
  for (int off = 32; off > 0; off >>= 1) vmax = fmaxf(vmax, __shfl_xor(vmax, off));
  const int wid = t >> 6;
  if ((t & 63) == 0) red[wid] = vmax;
  __syncthreads();
  vmax = fmaxf(fmaxf(red[0], red[1]), fmaxf(red[2], red[3]));
  float ev[4];
  float esum = 0.f;
#pragma unroll
  for (int j = 0; j < 4; j++) {
    int n = j * 256 + t;
    float e = (n < N3) ? __expf(vals[j] - vmax) : 0.f;
    ev[j] = e;
    esum += e;
  }
#pragma unroll
  for (int off = 32; off > 0; off >>= 1) esum += __shfl_xor(esum, off);
  if ((t & 63) == 0) red[4 + wid] = esum;
  __syncthreads();
  esum = red[4] + red[5] + red[6] + red[7];
  float inv = 1.f / esum;
#pragma unroll
  for (int j = 0; j < 4; j++) {
    int n = j * 256 + t;
    if (n < N3) out[(size_t)m * N3 + n] = ev[j] * inv;
  }
}

extern "C" void kernel_launch(void* const* d_in, const int* in_sizes, int n_in,
                              void* d_out, int out_size, void* d_ws, size_t ws_size,
                              hipStream_t stream) {
  const float* x = (const float*)d_in[0];
  const float* filters = (const float*)d_in[1];
  const float* W1 = (const float*)d_in[2];
  const float* b1 = (const float*)d_in[3];
  const float* W2 = (const float*)d_in[4];
  const float* b2 = (const float*)d_in[5];
  const float* Wo = (const float*)d_in[6];
  const float* bo = (const float*)d_in[7];
  float* out = (float*)d_out;

  float* ws = (float*)d_ws;
  float* s = ws;                                     // 64*50176
  float* flat = s + (size_t)Bsz * HS;                // 64*98592 (padded)
  float* partial = flat + (size_t)Bsz * FEATP;       // 257*64*512
  float* partial2 = partial + (size_t)NCH * Bsz * N1;// 8*64*512
  float* h1 = partial2 + (size_t)RG * Bsz * N1;      // 64*512
  float* h2 = h1 + (size_t)Bsz * N1;                 // 64*256
  float* logits = h2 + (size_t)Bsz * N2;             // 64*1000

  k_chsum<<<(Bsz * HS / 4 + 255) / 256, 256, 0, stream>>>((const float4*)x, (float4*)s);
  k_convpool<<<(Bsz * PP + 255) / 256, 256, 0, stream>>>(s, filters, flat);
  dim3 g1(4, NCH);
  k_gemm1<<<g1, 256, 0, stream>>>(flat, W1, partial);
  dim3 gr(Bsz * N1 / 256, RG);
  k_red1a<<<gr, 256, 0, stream>>>(partial, partial2);
  k_red1b<<<Bsz * N1 / 256, 256, 0, stream>>>(partial2, b1, h1);
  k_gemm2<<<Bsz * 4, 256, 0, stream>>>(h1, W2, b2, h2);
  k_logits<<<Bsz * 4, 256, 0, stream>>>(h2, Wo, bo, logits);
  k_softmax<<<Bsz, 256, 0, stream>>>(logits, out);
}

// Round 8
// 114.384 us; speedup vs baseline: 11.1350x; 1.2446x over previous
//
#include <hip/hip_runtime.h>
#include <math.h>

#define Bsz 64
#define Himg 224
#define HS (Himg*Himg)        // 50176
#define PW 111
#define PP (PW*PW)            // 12321
#define Fn 8
#define FEAT (Fn*PP)          // 98568
#define FEATP 98592           // FEAT padded to multiple of 32 (pad zeroed)
#define NT32_TOT 3081         // FEATP/32 k-tiles
#define KT32 12               // k32-tiles per split-K chunk (384 k)
#define NCH 257               // ceil(NT32_TOT/KT32)
#define N1 512
#define N2 256
#define N3 1000
#define RG 8                  // red1 k-groups

typedef short short8 __attribute__((ext_vector_type(8)));
typedef float f32x4 __attribute__((ext_vector_type(4)));

// split-float: x = hi + lo (both bf16, truncation split)
__device__ __forceinline__ void cvt_hilo(const float* v, short8& hi, short8& lo) {
#pragma unroll
  for (int j = 0; j < 8; j++) {
    unsigned u = __builtin_bit_cast(unsigned, v[j]);
    hi[j] = (short)(u >> 16);
    float hf = __builtin_bit_cast(float, u & 0xFFFF0000u);
    float r = v[j] - hf;
    lo[j] = (short)(__builtin_bit_cast(unsigned, r) >> 16);
  }
}

// pack one float into (bf16hi<<16)|bf16lo
__device__ __forceinline__ unsigned packhl(float f) {
  unsigned u = __builtin_bit_cast(unsigned, f);
  unsigned hi = u >> 16;
  float hf = __builtin_bit_cast(float, u & 0xFFFF0000u);
  float r = f - hf;
  unsigned lo = __builtin_bit_cast(unsigned, r) >> 16;
  return (hi << 16) | (lo & 0xFFFFu);
}

__device__ __forceinline__ uint4 pack4(float4 f) {
  uint4 o;
  o.x = packhl(f.x); o.y = packhl(f.y); o.z = packhl(f.z); o.w = packhl(f.w);
  return o;
}

// ---------------- channel sum: s[b,y,x] = sum_c x[b,c,y,x] (float4) --------
__global__ void k_chsum(const float4* __restrict__ x, float4* __restrict__ s) {
  int i = blockIdx.x * 256 + threadIdx.x;
  const int HQ = HS / 4;
  if (i >= Bsz * HQ) return;
  int b = i / HQ, p = i - b * HQ;
  const float4* xb = x + (size_t)b * 3 * HQ + p;
  float4 a = xb[0], c = xb[HQ], d = xb[2 * HQ];
  s[i] = make_float4(a.x + c.x + d.x, a.y + c.y + d.y,
                     a.z + c.z + d.z, a.w + c.w + d.w);
}

// ------------- conv3x3 (8 filt) + relu + maxpool2x2 -> flat (padded) -------
__global__ void k_convpool(const float* __restrict__ s, const float* __restrict__ filt,
                           float* __restrict__ flat) {
  int i = blockIdx.x * 256 + threadIdx.x;
  if (i < Bsz * (FEATP - FEAT))  // zero the 24-float pad of each batch row
    flat[(size_t)(i / 24) * FEATP + FEAT + (i % 24)] = 0.f;
  if (i >= Bsz * PP) return;
  int b = i / PP, r = i - b * PP;
  int py = r / PW, px = r - py * PW;
  const float* sp = s + (size_t)b * HS + (size_t)(2 * py) * Himg + 2 * px;
  float p[4][4];
#pragma unroll
  for (int dy = 0; dy < 4; dy++)
#pragma unroll
    for (int dx = 0; dx < 4; dx++)
      p[dy][dx] = sp[dy * Himg + dx];
  float* outb = flat + (size_t)b * FEATP + r;
#pragma unroll
  for (int f = 0; f < Fn; f++) {
    float mx = 0.f;
#pragma unroll
    for (int oy = 0; oy < 2; oy++)
#pragma unroll
      for (int ox = 0; ox < 2; ox++) {
        float c = 0.f;
#pragma unroll
        for (int dy = 0; dy < 3; dy++)
#pragma unroll
          for (int dx = 0; dx < 3; dx++)
            c = fmaf(p[oy + dy][ox + dx], filt[f * 9 + dy * 3 + dx], c);
        mx = fmaxf(mx, c);
      }
    outb[(size_t)f * PP] = mx;
  }
}

// ---------------- GEMM1 split-K via bf16 hi/lo MFMA + LDS-staged A ---------
// C = A(64 x K) @ W(K x 512): Ahi*Whi + Ahi*Wlo + Alo*Whi.
// grid (4 n-tiles of 128 cols, NCH chunks), block 256 thr = 4 waves.
// A tile (64x32) staged in LDS as packed (bf16hi<<16|bf16lo) u32, row-
// coalesced loads, XOR-swizzled granules (g ^= row&7) for balanced banks,
// double-buffered, 1 barrier/k-tile. B (per-wave 32 cols) from global with
// next-tile register prefetch. Wave w: cols w*32..+31, frags 4m x 2n.
__global__ void __launch_bounds__(256) k_gemm1(const float* __restrict__ A,
                                               const float* __restrict__ W,
                                               float* __restrict__ partial) {
  __shared__ unsigned As[2][64 * 32];   // 8 KB x2, [row][32 u32 swizzled]
  const int t = threadIdx.x;
  const int w = t >> 6;
  const int lane = t & 63;
  const int col0 = blockIdx.x * 128 + w * 32;
  const int c = blockIdx.y;
  const int tile0 = c * KT32;
  const int nt = min(KT32, NT32_TOT - tile0);
  const int lrow = lane & 15;
  const int lg8 = (lane >> 4) * 8;
  const int gr = lg8 >> 2;             // base granule for A-frag reads
  // A staging: lane covers rows sr, sr+8, granule sq (4 floats)
  const int sr = w * 16 + (lane >> 3);
  const int sq = lane & 7;
  const int sgs = ((sq ^ (sr & 7)) << 2);   // swizzled word offset in row
  const float* Ast = A + (size_t)sr * FEATP + sq * 4;

  f32x4 acc[4][2];
#pragma unroll
  for (int mf = 0; mf < 4; mf++)
#pragma unroll
    for (int nf = 0; nf < 2; nf++)
#pragma unroll
      for (int r = 0; r < 4; r++) acc[mf][nf][r] = 0.f;

  const float* Wcol = W + col0 + lrow;

  float bv0[8], bv1[8];
  float4 fa0, fa1;

  auto loadB = [&](int kb) {
#pragma unroll
    for (int j = 0; j < 8; j++) {
      int kk = kb + lg8 + j;
      kk = kk < FEAT ? kk : FEAT - 1;   // pad region: A is 0 there
      const float* wp = Wcol + (size_t)kk * N1;
      bv0[j] = wp[0];
      bv1[j] = wp[16];
    }
  };
  auto loadA = [&](int kb) {
    fa0 = *(const float4*)(Ast + kb);
    fa1 = *(const float4*)(Ast + (size_t)8 * FEATP + kb);
  };
  auto writeA = [&](int buf) {
    *(uint4*)&As[buf][sr * 32 + sgs] = pack4(fa0);
    *(uint4*)&As[buf][(sr + 8) * 32 + sgs] = pack4(fa1);
  };

  // prologue
  loadB(tile0 * 32);
  loadA(tile0 * 32);
  writeA(0);
  __syncthreads();

  for (int s = 0; s < nt; s++) {
    const int buf = s & 1;
    // convert current B to hi/lo fragments (frees bv for prefetch)
    short8 bhi[2], blo[2];
    cvt_hilo(bv0, bhi[0], blo[0]);
    cvt_hilo(bv1, bhi[1], blo[1]);
    const bool more = (s + 1) < nt;
    if (more) {                         // issue next-tile loads early
      const int kn = (tile0 + s + 1) * 32;
      loadB(kn);
      loadA(kn);
    }
    // MFMA phase from LDS
#pragma unroll
    for (int mf = 0; mf < 4; mf++) {
      const int r = mf * 16 + lrow;
      const int key = (r & 7);
      unsigned au[8];
      *(uint4*)(au + 0) = *(const uint4*)&As[buf][r * 32 + ((gr ^ key) << 2)];
      *(uint4*)(au + 4) = *(const uint4*)&As[buf][r * 32 + (((gr + 1) ^ key) << 2)];
      short8 ahi, alo;
#pragma unroll
      for (int j = 0; j < 8; j++) {
        ahi[j] = (short)(au[j] >> 16);
        alo[j] = (short)(au[j] & 0xFFFFu);
      }
#pragma unroll
      for (int nf = 0; nf < 2; nf++) {
        acc[mf][nf] = __builtin_amdgcn_mfma_f32_16x16x32_bf16(ahi, bhi[nf], acc[mf][nf], 0, 0, 0);
        acc[mf][nf] = __builtin_amdgcn_mfma_f32_16x16x32_bf16(ahi, blo[nf], acc[mf][nf], 0, 0, 0);
        acc[mf][nf] = __builtin_amdgcn_mfma_f32_16x16x32_bf16(alo, bhi[nf], acc[mf][nf], 0, 0, 0);
      }
    }
    if (more) writeA(buf ^ 1);          // compiler inserts vmcnt for fa regs
    __syncthreads();
  }

  const int drow = (lane >> 4) * 4;
#pragma unroll
  for (int mf = 0; mf < 4; mf++) {
#pragma unroll
    for (int nf = 0; nf < 2; nf++) {
      float* pp = partial + ((size_t)c * Bsz + mf * 16 + drow) * N1 + col0 + nf * 16 + lrow;
#pragma unroll
      for (int r = 0; r < 4; r++) pp[(size_t)r * N1] = acc[mf][nf][r];
    }
  }
}

// -------- red1a: partial[257][64][512] -> partial2[8][64*512] --------------
__global__ void k_red1a(const float* __restrict__ partial, float* __restrict__ partial2) {
  int i = blockIdx.x * 256 + threadIdx.x;   // elem 0..32767
  int g = blockIdx.y;
  int c0 = g * 33;
  int c1 = min(c0 + 33, NCH);
  float sum = 0.f;
  for (int c = c0; c < c1; c++) sum += partial[(size_t)c * Bsz * N1 + i];
  partial2[(size_t)g * Bsz * N1 + i] = sum;
}

// -------- red1b: sum 8 groups + bias + relu -> h1 [64,512] -----------------
__global__ void k_red1b(const float* __restrict__ partial2, const float* __restrict__ b1,
                        float* __restrict__ h1) {
  int i = blockIdx.x * 256 + threadIdx.x;
  float sum = 0.f;
#pragma unroll
  for (int g = 0; g < RG; g++) sum += partial2[(size_t)g * Bsz * N1 + i];
  h1[i] = fmaxf(sum + b1[i & (N1 - 1)], 0.f);
}

// -------- GEMM2: h2 = relu(h1 @ W2 + b2). grid 256 = (m, n-quarter) --------
__global__ void __launch_bounds__(256) k_gemm2(const float* __restrict__ h1,
                                               const float* __restrict__ W2,
                                               const float* __restrict__ b2,
                                               float* __restrict__ h2) {
  const int m = blockIdx.x >> 2;
  const int nq = blockIdx.x & 3;
  const int t = threadIdx.x;
  __shared__ float a[N1];
  __shared__ float red[4][64];
  a[t] = h1[(size_t)m * N1 + t];
  a[256 + t] = h1[(size_t)m * N1 + 256 + t];
  __syncthreads();
  const int col = nq * 64 + (t & 63);
  const int ks = (t >> 6) * 128;
  float sum = 0.f;
#pragma unroll 8
  for (int k = 0; k < 128; k++)
    sum = fmaf(a[ks + k], W2[(size_t)(ks + k) * N2 + col], sum);
  red[t >> 6][t & 63] = sum;
  __syncthreads();
  if (t < 64) {
    float tot = red[0][t] + red[1][t] + red[2][t] + red[3][t] + b2[nq * 64 + t];
    h2[(size_t)m * N2 + nq * 64 + t] = fmaxf(tot, 0.f);
  }
}

// -------- logits = h2 @ Wo + bo. grid 256 = (m, n-chunk of 250) ------------
__global__ void __launch_bounds__(256) k_logits(const float* __restrict__ h2,
                                                const float* __restrict__ Wo,
                                                const float* __restrict__ bo,
                                                float* __restrict__ logits) {
  const int m = blockIdx.x >> 2;
  const int nc = blockIdx.x & 3;
  const int t = threadIdx.x;
  __shared__ float a[N2];
  a[t] = h2[(size_t)m * N2 + t];
  __syncthreads();
  const int col = nc * 250 + t;
  if (t >= 250) return;
  float sum = bo[col];
#pragma unroll 8
  for (int k = 0; k < N2; k++)
    sum = fmaf(a[k], Wo[(size_t)k * N3 + col], sum);
  logits[(size_t)m * N3 + col] = sum;
}

// -------- softmax over logits rows -> out ----------------------------------
__global__ void __launch_bounds__(256) k_softmax(const float* __restrict__ logits,
                                                 float* __restrict__ out) {
  const int m = blockIdx.x;
  const int t = threadIdx.x;
  __shared__ float red[8];
  float vals[4];
  float vmax = -3.4e38f;
#pragma unroll
  for (int j = 0; j < 4; j++) {
    int n = j * 256 + t;
    vals[j] = (n < N3) ? logits[(size_t)m * N3 + n] : -3.4e38f;
    vmax = fmaxf(vmax, vals[j]);
  }
#pragma unroll
  for (int off = 32; off > 0; off >>= 1) vmax = fmaxf(vmax, __shfl_xor(vmax, off));
  const int wid = t >> 6;
  if ((t & 63) == 0) red[wid] = vmax;
  __syncthreads();
  vmax = fmaxf(fmaxf(red[0], red[1]), fmaxf(red[2], red[3]));
  float ev[4];
  float esum = 0.f;
#pragma unroll
  for (int j = 0; j < 4; j++) {
    int n = j * 256 + t;
    float e = (n < N3) ? __expf(vals[j] - vmax) : 0.f;
    ev[j] = e;
    esum += e;
  }
#pragma unroll
  for (int off = 32; off > 0; off >>= 1) esum += __shfl_xor(esum, off);
  if ((t & 63) == 0) red[4 + wid] = esum;
  __syncthreads();
  esum = red[4] + red[5] + red[6] + red[7];
  float inv = 1.f / esum;
#pragma unroll
  for (int j = 0; j < 4; j++) {
    int n = j * 256 + t;
    if (n < N3) out[(size_t)m * N3 + n] = ev[j] * inv;
  }
}

extern "C" void kernel_launch(void* const* d_in, const int* in_sizes, int n_in,
                              void* d_out, int out_size, void* d_ws, size_t ws_size,
                              hipStream_t stream) {
  const float* x = (const float*)d_in[0];
  const float* filters = (const float*)d_in[1];
  const float* W1 = (const float*)d_in[2];
  const float* b1 = (const float*)d_in[3];
  const float* W2 = (const float*)d_in[4];
  const float* b2 = (const float*)d_in[5];
  const float* Wo = (const float*)d_in[6];
  const float* bo = (const float*)d_in[7];
  float* out = (float*)d_out;

  float* ws = (float*)d_ws;
  float* s = ws;                                     // 64*50176
  float* flat = s + (size_t)Bsz * HS;                // 64*98592 (padded)
  float* partial = flat + (size_t)Bsz * FEATP;       // 257*64*512
  float* partial2 = partial + (size_t)NCH * Bsz * N1;// 8*64*512
  float* h1 = partial2 + (size_t)RG * Bsz * N1;      // 64*512
  float* h2 = h1 + (size_t)Bsz * N1;                 // 64*256
  float* logits = h2 + (size_t)Bsz * N2;             // 64*1000

  k_chsum<<<(Bsz * HS / 4 + 255) / 256, 256, 0, stream>>>((const float4*)x, (float4*)s);
  k_convpool<<<(Bsz * PP + 255) / 256, 256, 0, stream>>>(s, filters, flat);
  dim3 g1(4, NCH);
  k_gemm1<<<g1, 256, 0, stream>>>(flat, W1, partial);
  dim3 gr(Bsz * N1 / 256, RG);
  k_red1a<<<gr, 256, 0, stream>>>(partial, partial2);
  k_red1b<<<Bsz * N1 / 256, 256, 0, stream>>>(partial2, b1, h1);
  k_gemm2<<<Bsz * 4, 256, 0, stream>>>(h1, W2, b2, h2);
  k_logits<<<Bsz * 4, 256, 0, stream>>>(h2, Wo, bo, logits);
  k_softmax<<<Bsz, 256, 0, stream>>>(logits, out);
}

// Round 9
// 112.860 us; speedup vs baseline: 11.2854x; 1.0135x over previous
//
#include <hip/hip_runtime.h>
#include <math.h>

#define Bsz 64
#define Himg 224
#define HS (Himg*Himg)        // 50176
#define PW 111
#define PP (PW*PW)            // 12321
#define Fn 8
#define FEAT (Fn*PP)          // 98568
#define FEATP 98592           // FEAT padded to multiple of 32 (pad zeroed)
#define KC 32                 // k per tile
#define NT32_TOT 3081         // FEATP/32 k-tiles
#define KT32 16               // k32-tiles per split-K chunk (512 k)
#define NCH 193               // ceil(NT32_TOT/KT32)
#define N1 512
#define N2 256
#define N3 1000
#define RG 8                  // red1 k-groups

typedef short short8 __attribute__((ext_vector_type(8)));
typedef float f32x4 __attribute__((ext_vector_type(4)));

// async global->LDS, 16B per lane; LDS base wave-uniform, global src per-lane
#define GLOAD_LDS16(g, l)                                                     \
  __builtin_amdgcn_global_load_lds(                                           \
      (const __attribute__((address_space(1))) void*)(g),                     \
      (__attribute__((address_space(3))) void*)(l), 16, 0, 0)

// split-float: x = hi + lo (both bf16, truncation split)
__device__ __forceinline__ void cvt_hilo(const float* v, short8& hi, short8& lo) {
#pragma unroll
  for (int j = 0; j < 8; j++) {
    unsigned u = __builtin_bit_cast(unsigned, v[j]);
    hi[j] = (short)(u >> 16);
    float hf = __builtin_bit_cast(float, u & 0xFFFF0000u);
    float r = v[j] - hf;
    lo[j] = (short)(__builtin_bit_cast(unsigned, r) >> 16);
  }
}

// pack one float into (bf16hi<<16)|bf16lo
__device__ __forceinline__ unsigned packhl(float f) {
  unsigned u = __builtin_bit_cast(unsigned, f);
  unsigned hi = u >> 16;
  float hf = __builtin_bit_cast(float, u & 0xFFFF0000u);
  float r = f - hf;
  unsigned lo = __builtin_bit_cast(unsigned, r) >> 16;
  return (hi << 16) | (lo & 0xFFFFu);
}

__device__ __forceinline__ uint4 pack4(float4 f) {
  uint4 o;
  o.x = packhl(f.x); o.y = packhl(f.y); o.z = packhl(f.z); o.w = packhl(f.w);
  return o;
}

// ------- fused: channel-sum + conv3x3 (8 filt) + relu + maxpool -> flat ----
__global__ void k_convpool(const float* __restrict__ x, const float* __restrict__ filt,
                           float* __restrict__ flat) {
  int i = blockIdx.x * 256 + threadIdx.x;
  if (i < Bsz * (FEATP - FEAT))  // zero the 24-float pad of each batch row
    flat[(size_t)(i / 24) * FEATP + FEAT + (i % 24)] = 0.f;
  if (i >= Bsz * PP) return;
  int b = i / PP, r = i - b * PP;
  int py = r / PW, px = r - py * PW;
  const float* xb = x + (size_t)b * 3 * HS + (size_t)(2 * py) * Himg + 2 * px;
  float p[4][4];
#pragma unroll
  for (int dy = 0; dy < 4; dy++) {
    const float* row = xb + dy * Himg;
    float2 a0 = *(const float2*)(row);
    float2 a1 = *(const float2*)(row + 2);
    float2 b0 = *(const float2*)(row + HS);
    float2 b1 = *(const float2*)(row + HS + 2);
    float2 c0 = *(const float2*)(row + 2 * HS);
    float2 c1 = *(const float2*)(row + 2 * HS + 2);
    p[dy][0] = a0.x + b0.x + c0.x;
    p[dy][1] = a0.y + b0.y + c0.y;
    p[dy][2] = a1.x + b1.x + c1.x;
    p[dy][3] = a1.y + b1.y + c1.y;
  }
  float* outb = flat + (size_t)b * FEATP + r;
#pragma unroll
  for (int f = 0; f < Fn; f++) {
    float mx = 0.f;
#pragma unroll
    for (int oy = 0; oy < 2; oy++)
#pragma unroll
      for (int ox = 0; ox < 2; ox++) {
        float c = 0.f;
#pragma unroll
        for (int dy = 0; dy < 3; dy++)
#pragma unroll
          for (int dx = 0; dx < 3; dx++)
            c = fmaf(p[oy + dy][ox + dx], filt[f * 9 + dy * 3 + dx], c);
        mx = fmaxf(mx, c);
      }
    outb[(size_t)f * PP] = mx;
  }
}

// ---------------- GEMM1 split-K via bf16 hi/lo MFMA ------------------------
// C = A(64 x K) @ W(K x 512): Ahi*Whi + Ahi*Wlo + Alo*Whi.
// grid (4 n-tiles of 128 cols, NCH chunks), block 256 thr = 4 waves.
// W tile (32x128 fp32) staged direct-to-LDS via global_load_lds (4 coalesced
// 1KB loads/wave), double-buffered; B frags read as ds_read_b32.
// A tile (64x32) reg-staged as packed (hi<<16|lo) u32, XOR-swizzled granules.
// One barrier per k-tile. Wave w: cols w*32..+31, frags 4m x 2n.
__global__ void __launch_bounds__(256) k_gemm1(const float* __restrict__ A,
                                               const float* __restrict__ W,
                                               float* __restrict__ partial) {
  __shared__ float Wl[2][KC][128];      // 16 KB x2
  __shared__ unsigned As[2][64 * 32];   // 8 KB x2, [row][32 u32 swizzled]
  const int t = threadIdx.x;
  const int wv = t >> 6;
  const int lane = t & 63;
  const int col0b = blockIdx.x * 128;
  const int c = blockIdx.y;
  const int tile0 = c * KT32;
  const int nt = min(KT32, NT32_TOT - tile0);
  const int lrow = lane & 15;
  const int lg8 = (lane >> 4) * 8;
  const int gr = lg8 >> 2;             // base granule for A-frag reads
  // A staging: lane covers rows sr, sr+8, granule sq (4 floats)
  const int sr = wv * 16 + (lane >> 3);
  const int sq = lane & 7;
  const int sgs = ((sq ^ (sr & 7)) << 2);
  const float* Ast = A + (size_t)sr * FEATP + sq * 4;
  // W staging: wave wv covers k-rows 8wv..8wv+7, 4 gloads of 2 rows
  const int wsr = lane >> 5;           // 0..1
  const int wsc = (lane & 31) * 4;
  const int wcol = wv * 32 + lrow;     // this wave's B col base (nf=0)

  f32x4 acc[4][2];
#pragma unroll
  for (int mf = 0; mf < 4; mf++)
#pragma unroll
    for (int nf = 0; nf < 2; nf++)
#pragma unroll
      for (int r = 0; r < 4; r++) acc[mf][nf][r] = 0.f;

  float4 fa0, fa1;

#define STAGE_W(buf, kt)                                                      \
  {                                                                           \
    const int kb = (kt) * KC + wv * 8;                                        \
    _Pragma("unroll")                                                         \
    for (int p = 0; p < 4; p++) {                                             \
      int krow = kb + 2 * p + wsr;                                            \
      krow = krow < FEAT ? krow : FEAT - 1;  /* pad rows: A is 0 there */     \
      GLOAD_LDS16(W + (size_t)krow * N1 + col0b + wsc,                        \
                  &Wl[buf][wv * 8 + 2 * p][0]);                               \
    }                                                                         \
  }

  auto loadA = [&](int kb) {
    fa0 = *(const float4*)(Ast + kb);
    fa1 = *(const float4*)(Ast + (size_t)8 * FEATP + kb);
  };
  auto writeA = [&](int buf) {
    *(uint4*)&As[buf][sr * 32 + sgs] = pack4(fa0);
    *(uint4*)&As[buf][(sr + 8) * 32 + sgs] = pack4(fa1);
  };

  // prologue
  STAGE_W(0, tile0)
  loadA(tile0 * KC);
  writeA(0);
  __syncthreads();

  for (int s = 0; s < nt; s++) {
    const int buf = s & 1;
    const bool more = (s + 1) < nt;
    if (more) {                         // next-tile loads, in flight all phase
      STAGE_W(buf ^ 1, tile0 + s + 1)
      loadA((tile0 + s + 1) * KC);
    }
    // ---- B fragments from LDS + hi/lo convert ----
    float bv0[8], bv1[8];
#pragma unroll
    for (int j = 0; j < 8; j++) {
      bv0[j] = Wl[buf][lg8 + j][wcol];
      bv1[j] = Wl[buf][lg8 + j][wcol + 16];
    }
    short8 bhi[2], blo[2];
    cvt_hilo(bv0, bhi[0], blo[0]);
    cvt_hilo(bv1, bhi[1], blo[1]);
    // ---- A fragments + MFMA ----
#pragma unroll
    for (int mf = 0; mf < 4; mf++) {
      const int r = mf * 16 + lrow;
      const int key = (r & 7);
      unsigned au[8];
      *(uint4*)(au + 0) = *(const uint4*)&As[buf][r * 32 + ((gr ^ key) << 2)];
      *(uint4*)(au + 4) = *(const uint4*)&As[buf][r * 32 + (((gr + 1) ^ key) << 2)];
      short8 ahi, alo;
#pragma unroll
      for (int j = 0; j < 8; j++) {
        ahi[j] = (short)(au[j] >> 16);
        alo[j] = (short)(au[j] & 0xFFFFu);
      }
#pragma unroll
      for (int nf = 0; nf < 2; nf++) {
        acc[mf][nf] = __builtin_amdgcn_mfma_f32_16x16x32_bf16(ahi, bhi[nf], acc[mf][nf], 0, 0, 0);
        acc[mf][nf] = __builtin_amdgcn_mfma_f32_16x16x32_bf16(ahi, blo[nf], acc[mf][nf], 0, 0, 0);
        acc[mf][nf] = __builtin_amdgcn_mfma_f32_16x16x32_bf16(alo, bhi[nf], acc[mf][nf], 0, 0, 0);
      }
    }
    if (more) writeA(buf ^ 1);
    __syncthreads();
  }

  const int drow = (lane >> 4) * 4;
#pragma unroll
  for (int mf = 0; mf < 4; mf++) {
#pragma unroll
    for (int nf = 0; nf < 2; nf++) {
      float* pp = partial + ((size_t)c * Bsz + mf * 16 + drow) * N1 +
                  col0b + wv * 32 + nf * 16 + lrow;
#pragma unroll
      for (int r = 0; r < 4; r++) pp[(size_t)r * N1] = acc[mf][nf][r];
    }
  }
}

// -------- red1a: partial[193][64][512] -> partial2[8][64*512] --------------
__global__ void k_red1a(const float* __restrict__ partial, float* __restrict__ partial2) {
  int i = blockIdx.x * 256 + threadIdx.x;   // elem 0..32767
  int g = blockIdx.y;
  int c0 = g * 25;
  int c1 = min(c0 + 25, NCH);
  float sum = 0.f;
  for (int c = c0; c < c1; c++) sum += partial[(size_t)c * Bsz * N1 + i];
  partial2[(size_t)g * Bsz * N1 + i] = sum;
}

// -------- red1b: sum 8 groups + bias + relu -> h1 [64,512] -----------------
__global__ void k_red1b(const float* __restrict__ partial2, const float* __restrict__ b1,
                        float* __restrict__ h1) {
  int i = blockIdx.x * 256 + threadIdx.x;
  float sum = 0.f;
#pragma unroll
  for (int g = 0; g < RG; g++) sum += partial2[(size_t)g * Bsz * N1 + i];
  h1[i] = fmaxf(sum + b1[i & (N1 - 1)], 0.f);
}

// -------- GEMM2: h2 = relu(h1 @ W2 + b2). grid 256 = (m, n-quarter) --------
__global__ void __launch_bounds__(256) k_gemm2(const float* __restrict__ h1,
                                               const float* __restrict__ W2,
                                               const float* __restrict__ b2,
                                               float* __restrict__ h2) {
  const int m = blockIdx.x >> 2;
  const int nq = blockIdx.x & 3;
  const int t = threadIdx.x;
  __shared__ float a[N1];
  __shared__ float red[4][64];
  a[t] = h1[(size_t)m * N1 + t];
  a[256 + t] = h1[(size_t)m * N1 + 256 + t];
  __syncthreads();
  const int col = nq * 64 + (t & 63);
  const int ks = (t >> 6) * 128;
  float sum = 0.f;
#pragma unroll 8
  for (int k = 0; k < 128; k++)
    sum = fmaf(a[ks + k], W2[(size_t)(ks + k) * N2 + col], sum);
  red[t >> 6][t & 63] = sum;
  __syncthreads();
  if (t < 64) {
    float tot = red[0][t] + red[1][t] + red[2][t] + red[3][t] + b2[nq * 64 + t];
    h2[(size_t)m * N2 + nq * 64 + t] = fmaxf(tot, 0.f);
  }
}

// -------- logits = h2 @ Wo + bo. grid 256 = (m, n-chunk of 250) ------------
__global__ void __launch_bounds__(256) k_logits(const float* __restrict__ h2,
                                                const float* __restrict__ Wo,
                                                const float* __restrict__ bo,
                                                float* __restrict__ logits) {
  const int m = blockIdx.x >> 2;
  const int nc = blockIdx.x & 3;
  const int t = threadIdx.x;
  __shared__ float a[N2];
  a[t] = h2[(size_t)m * N2 + t];
  __syncthreads();
  const int col = nc * 250 + t;
  if (t >= 250) return;
  float sum = bo[col];
#pragma unroll 8
  for (int k = 0; k < N2; k++)
    sum = fmaf(a[k], Wo[(size_t)k * N3 + col], sum);
  logits[(size_t)m * N3 + col] = sum;
}

// -------- softmax over logits rows -> out ----------------------------------
__global__ void __launch_bounds__(256) k_softmax(const float* __restrict__ logits,
                                                 float* __restrict__ out) {
  const int m = blockIdx.x;
  const int t = threadIdx.x;
  __shared__ float red[8];
  float vals[4];
  float vmax = -3.4e38f;
#pragma unroll
  for (int j = 0; j < 4; j++) {
    int n = j * 256 + t;
    vals[j] = (n < N3) ? logits[(size_t)m * N3 + n] : -3.4e38f;
    vmax = fmaxf(vmax, vals[j]);
  }
#pragma unroll
  for (int off = 32; off > 0; off >>= 1) vmax = fmaxf(vmax, __shfl_xor(vmax, off));
  const int wid = t >> 6;
  if ((t & 63) == 0) red[wid] = vmax;
  __syncthreads();
  vmax = fmaxf(fmaxf(red[0], red[1]), fmaxf(red[2], red[3]));
  float ev[4];
  float esum = 0.f;
#pragma unroll
  for (int j = 0; j < 4; j++) {
    int n = j * 256 + t;
    float e = (n < N3) ? __expf(vals[j] - vmax) : 0.f;
    ev[j] = e;
    esum += e;
  }
#pragma unroll
  for (int off = 32; off > 0; off >>= 1) esum += __shfl_xor(esum, off);
  if ((t & 63) == 0) red[4 + wid] = esum;
  __syncthreads();
  esum = red[4] + red[5] + red[6] + red[7];
  float inv = 1.f / esum;
#pragma unroll
  for (int j = 0; j < 4; j++) {
    int n = j * 256 + t;
    if (n < N3) out[(size_t)m * N3 + n] = ev[j] * inv;
  }
}

extern "C" void kernel_launch(void* const* d_in, const int* in_sizes, int n_in,
                              void* d_out, int out_size, void* d_ws, size_t ws_size,
                              hipStream_t stream) {
  const float* x = (const float*)d_in[0];
  const float* filters = (const float*)d_in[1];
  const float* W1 = (const float*)d_in[2];
  const float* b1 = (const float*)d_in[3];
  const float* W2 = (const float*)d_in[4];
  const float* b2 = (const float*)d_in[5];
  const float* Wo = (const float*)d_in[6];
  const float* bo = (const float*)d_in[7];
  float* out = (float*)d_out;

  float* ws = (float*)d_ws;
  float* flat = ws;                                  // 64*98592 (padded)
  float* partial = flat + (size_t)Bsz * FEATP;       // 193*64*512
  float* partial2 = partial + (size_t)NCH * Bsz * N1;// 8*64*512
  float* h1 = partial2 + (size_t)RG * Bsz * N1;      // 64*512
  float* h2 = h1 + (size_t)Bsz * N1;                 // 64*256
  float* logits = h2 + (size_t)Bsz * N2;             // 64*1000

  k_convpool<<<(Bsz * PP + 255) / 256, 256, 0, stream>>>(x, filters, flat);
  dim3 g1(4, NCH);
  k_gemm1<<<g1, 256, 0, stream>>>(flat, W1, partial);
  dim3 gr(Bsz * N1 / 256, RG);
  k_red1a<<<gr, 256, 0, stream>>>(partial, partial2);
  k_red1b<<<Bsz * N1 / 256, 256, 0, stream>>>(partial2, b1, h1);
  k_gemm2<<<Bsz * 4, 256, 0, stream>>>(h1, W2, b2, h2);
  k_logits<<<Bsz * 4, 256, 0, stream>>>(h2, Wo, bo, logits);
  k_softmax<<<Bsz, 256, 0, stream>>>(logits, out);
}